// Round 12
// baseline (3620.156 us; speedup 1.0000x reference)
//
#include <hip/hip_runtime.h>
#include <hip/hip_bf16.h>

typedef __attribute__((ext_vector_type(8))) short short8v;   // 8 bf16 = 16 B
typedef __attribute__((ext_vector_type(4))) float f32x4;

union SV { short8v v; unsigned short u[8]; };
union FU { float f; unsigned u; };
union QF { unsigned long long q[4]; float4 v[2]; };

// Truncation split: x ~= hi + lo, residual <= 2^-16 |x|.
__device__ __forceinline__ void split2(float x, unsigned short& hi, unsigned short& lo) {
    FU a; a.f = x;
    hi = (unsigned short)(a.u >> 16);
    FU h; h.u = a.u & 0xffff0000u;
    FU r; r.f = x - h.f;              // exact
    lo = (unsigned short)(r.u >> 16);
}
__device__ __forceinline__ void split8(const float4 a0, const float4 a1, SV& h, SV& l) {
    split2(a0.x, h.u[0], l.u[0]); split2(a0.y, h.u[1], l.u[1]);
    split2(a0.z, h.u[2], l.u[2]); split2(a0.w, h.u[3], l.u[3]);
    split2(a1.x, h.u[4], l.u[4]); split2(a1.y, h.u[5], l.u[5]);
    split2(a1.z, h.u[6], l.u[6]); split2(a1.w, h.u[7], l.u[7]);
}
__device__ __forceinline__ float sigmoidf_(float x) {
    return 1.0f / (1.0f + __expf(-x));
}

// Agent-scope (LLC-coherent, L2-bypassing) h accessors — all cross-step h
// traffic, so no cache-maintenance fences are needed anywhere.
__device__ __forceinline__ unsigned long long h_load64(const float* p) {
    return __hip_atomic_load((const unsigned long long*)p,
                             __ATOMIC_RELAXED, __HIP_MEMORY_SCOPE_AGENT);
}
__device__ __forceinline__ float h_load32(const float* p) {
    FU u; u.u = __hip_atomic_load((const unsigned*)p,
                                  __ATOMIC_RELAXED, __HIP_MEMORY_SCOPE_AGENT);
    return u.f;
}
__device__ __forceinline__ void h_store32(float* p, float v) {
    FU u; u.f = v;
    __hip_atomic_store((unsigned*)p, u.u,
                       __ATOMIC_RELAXED, __HIP_MEMORY_SCOPE_AGENT);
}

// Per-rt-group barrier — VERBATIM the R9/R10 replay-proven shape: arrive and
// poll adjacent, tightly fenced; NO work inside. (R11 split this with ~2us of
// gi work between arrive and poll and diverged on graph replays — the only
// structural delta from the proven protocol, reverted here.)
__device__ __forceinline__ void group_barrier(unsigned* gf, const int ct,
                                              const unsigned gen) {
    __builtin_amdgcn_s_waitcnt(0);
    __syncthreads();
    __atomic_signal_fence(__ATOMIC_SEQ_CST);
    if (threadIdx.x == 0)
        __hip_atomic_store(&gf[ct], gen,
                           __ATOMIC_RELAXED, __HIP_MEMORY_SCOPE_AGENT);
    if (threadIdx.x < 16) {
        const unsigned long long* f64 = (const unsigned long long*)gf;
        for (;;) {
            unsigned long long v = __hip_atomic_load(
                &f64[threadIdx.x], __ATOMIC_RELAXED, __HIP_MEMORY_SCOPE_AGENT);
            if (((unsigned)v >= gen) && ((unsigned)(v >> 32) >= gen)) break;
            __builtin_amdgcn_s_sleep(1);
        }
    }
    __atomic_signal_fence(__ATOMIC_SEQ_CST);
    __syncthreads();
}

// ---- split-cast weights f32 -> (hi, lo) bf16, once ----
__global__ __launch_bounds__(256) void cast_split(
    const float* __restrict__ in, unsigned short* __restrict__ hi,
    unsigned short* __restrict__ lo, int n4)
{
    int i = blockIdx.x * 256 + threadIdx.x;
    if (i < n4) {
        float4 v = ((const float4*)in)[i];
        ushort4 h, l;
        split2(v.x, h.x, l.x); split2(v.y, h.y, l.y);
        split2(v.z, h.z, l.z); split2(v.w, h.w, l.w);
        ((ushort4*)hi)[i] = h;
        ((ushort4*)lo)[i] = l;
    }
}

// ---- gi slice: g{r,z,n} = (X[step] @ w_ih^T + b_ih)[row, col] for this
// thread's epilogue element. Same K-split-4 + LDS-exchange layout as the
// recurrent part, so producer thread == consumer thread; gi lives in regs.
__device__ __forceinline__ void gi_compute(
    float* accs_g,                             // LDS [4][3][4][64]
    const float* __restrict__ X,               // [S*256, 512] fp32
    const unsigned short* __restrict__ wihH,
    const unsigned short* __restrict__ wihL,
    const int step, const int tid, const int rt, const int ct,
    const float bir, const float biz, const float bin,
    float& gr, float& gz, float& gn)
{
    const int l = tid & 63, wv = tid >> 6;
    const int arow = l & 15, ksl = l >> 4, kbase = wv * 128;
    const int c0 = ct * 16, row0 = rt * 16;
    const float* xa = X + ((size_t)step * 256 + row0 + arow) * 512 + kbase + ksl * 8;
    f32x4 acc[3] = {};
#pragma unroll
    for (int j = 0; j < 4; ++j) {
        const float4 x0 = *(const float4*)(xa + j * 32);
        const float4 x1 = *(const float4*)(xa + j * 32 + 4);
        SV ah, al;
        split8(x0, x1, ah, al);
        const int ko = kbase + j * 32 + ksl * 8;
#pragma unroll
        for (int g = 0; g < 3; ++g) {
            const size_t wo = (size_t)((g << 9) + c0 + arow) * 512 + ko;
            const short8v bh = *(const short8v*)(wihH + wo);
            const short8v bl = *(const short8v*)(wihL + wo);
            acc[g] = __builtin_amdgcn_mfma_f32_16x16x32_bf16(ah.v, bh, acc[g], 0, 0, 0);
            acc[g] = __builtin_amdgcn_mfma_f32_16x16x32_bf16(ah.v, bl, acc[g], 0, 0, 0);
            acc[g] = __builtin_amdgcn_mfma_f32_16x16x32_bf16(al.v, bh, acc[g], 0, 0, 0);
        }
    }
#pragma unroll
    for (int g = 0; g < 3; ++g)
#pragma unroll
        for (int rg = 0; rg < 4; ++rg)
            accs_g[((wv * 3 + g) * 4 + rg) * 64 + l] = acc[g][rg];
    __syncthreads();
    gr = accs_g[((0 * 3 + 0) * 4 + wv) * 64 + l]
       + accs_g[((1 * 3 + 0) * 4 + wv) * 64 + l]
       + accs_g[((2 * 3 + 0) * 4 + wv) * 64 + l]
       + accs_g[((3 * 3 + 0) * 4 + wv) * 64 + l] + bir;
    gz = accs_g[((0 * 3 + 1) * 4 + wv) * 64 + l]
       + accs_g[((1 * 3 + 1) * 4 + wv) * 64 + l]
       + accs_g[((2 * 3 + 1) * 4 + wv) * 64 + l]
       + accs_g[((3 * 3 + 1) * 4 + wv) * 64 + l] + biz;
    gn = accs_g[((0 * 3 + 2) * 4 + wv) * 64 + l]
       + accs_g[((1 * 3 + 2) * 4 + wv) * 64 + l]
       + accs_g[((2 * 3 + 2) * 4 + wv) * 64 + l]
       + accs_g[((3 * 3 + 2) * 4 + wv) * 64 + l] + bin;
}

// ---- recurrent slice: h(t-1) @ w_hh^T partials, K-split over 4 waves,
// fragments direct from global (h via LLC atomics, w from L2).
__device__ __forceinline__ void recur_compute(
    float* accs_r,                             // LDS [4][3][4][64]
    const unsigned short* __restrict__ whhH,
    const unsigned short* __restrict__ whhL,
    const float* __restrict__ hold,
    const int tid, const int rt, const int ct,
    float& s0, float& s1, float& s2)
{
    const int l = tid & 63, wv = tid >> 6;
    const int arow = l & 15, ksl = l >> 4, kbase = wv * 128;
    const int c0 = ct * 16, row0 = rt * 16;

    unsigned long long a_raw[4][4];
    const float* ha = hold + (size_t)(row0 + arow) * 512 + kbase + ksl * 8;
#pragma unroll
    for (int j = 0; j < 4; ++j)
#pragma unroll
        for (int q = 0; q < 4; ++q)
            a_raw[j][q] = h_load64(ha + j * 32 + q * 2);

    f32x4 acc[3] = {};
#pragma unroll
    for (int j = 0; j < 4; ++j) {
        QF buf;
#pragma unroll
        for (int q = 0; q < 4; ++q) buf.q[q] = a_raw[j][q];
        SV ah, al;
        split8(buf.v[0], buf.v[1], ah, al);
        const int ko = kbase + j * 32 + ksl * 8;
#pragma unroll
        for (int g = 0; g < 3; ++g) {
            const size_t wo = (size_t)((g << 9) + c0 + arow) * 512 + ko;
            const short8v bh = *(const short8v*)(whhH + wo);
            const short8v bl = *(const short8v*)(whhL + wo);
            acc[g] = __builtin_amdgcn_mfma_f32_16x16x32_bf16(ah.v, bh, acc[g], 0, 0, 0);
            acc[g] = __builtin_amdgcn_mfma_f32_16x16x32_bf16(ah.v, bl, acc[g], 0, 0, 0);
            acc[g] = __builtin_amdgcn_mfma_f32_16x16x32_bf16(al.v, bh, acc[g], 0, 0, 0);
        }
    }
#pragma unroll
    for (int g = 0; g < 3; ++g)
#pragma unroll
        for (int rg = 0; rg < 4; ++rg)
            accs_r[((wv * 3 + g) * 4 + rg) * 64 + l] = acc[g][rg];
    __syncthreads();
    s0 = accs_r[((0 * 3 + 0) * 4 + wv) * 64 + l]
       + accs_r[((1 * 3 + 0) * 4 + wv) * 64 + l]
       + accs_r[((2 * 3 + 0) * 4 + wv) * 64 + l]
       + accs_r[((3 * 3 + 0) * 4 + wv) * 64 + l];
    s1 = accs_r[((0 * 3 + 1) * 4 + wv) * 64 + l]
       + accs_r[((1 * 3 + 1) * 4 + wv) * 64 + l]
       + accs_r[((2 * 3 + 1) * 4 + wv) * 64 + l]
       + accs_r[((3 * 3 + 1) * 4 + wv) * 64 + l];
    s2 = accs_r[((0 * 3 + 2) * 4 + wv) * 64 + l]
       + accs_r[((1 * 3 + 2) * 4 + wv) * 64 + l]
       + accs_r[((2 * 3 + 2) * 4 + wv) * 64 + l]
       + accs_r[((3 * 3 + 2) * 4 + wv) * 64 + l];
}

// ---- Fused persistent kernel — all 256 steps, gi in registers. ----
// Grid 512 x 256 thr (16 rt-groups x 32 ct; 4 waves each own a K-quarter).
// Per step: recur -> epilogue (uses gi computed LAST step) -> h store ->
// gi[t+1] (X-only, no h access) -> group_barrier (R10-proven, atomic shape).
__global__ __launch_bounds__(256, 2) void gru_coop(
    const float* __restrict__ X,               // [256*256, 512] input
    const unsigned short* __restrict__ wihH,
    const unsigned short* __restrict__ wihL,
    const unsigned short* __restrict__ whhH,
    const unsigned short* __restrict__ whhL,
    const float* __restrict__ bih,
    const float* __restrict__ bhh,
    float* __restrict__ hA, float* __restrict__ hB,
    unsigned* __restrict__ flags,              // 16 groups x 32 u32
    const int tc)
{
    __shared__ float accs_r[4 * 3 * 4 * 64];   // 12 KB recurrent partials
    __shared__ float accs_g[4 * 3 * 4 * 64];   // 12 KB gi partials
    const int tid = threadIdx.x;
    const int l = tid & 63, wv = tid >> 6;
    const int ct = blockIdx.x & 31;
    const int rt = blockIdx.x >> 5;
    unsigned* gf = flags + rt * 32;

    // Loop-invariant per-thread constants (epilogue element (row, col)).
    const int col = ct * 16 + (l & 15);
    const int row = rt * 16 + ((l >> 4) << 2) + wv;
    const float bir = bih[col], biz = bih[512 + col], bin = bih[1024 + col];
    const float bhr = bhh[col], bhz = bhh[512 + col], bhn = bhh[1024 + col];

    // Prologue: gi for step 0 (X-GEMM only; no cross-block dependency).
    float gir, giz, gin;
    gi_compute(accs_g, X, wihH, wihL, 0, tid, rt, ct, bir, biz, bin,
               gir, giz, gin);

    for (int t = 0; t < tc; ++t) {
        const float* hold = (t & 1) ? hB : hA;
        float* hnew = (t & 1) ? hA : hB;

        float s0, s1, s2;
        recur_compute(accs_r, whhH, whhL, hold, tid, rt, ct, s0, s1, s2);

        const float hv = h_load32(hold + (size_t)row * 512 + col);
        const float r = sigmoidf_(gir + s0 + bhr);
        const float z = sigmoidf_(giz + s1 + bhz);
        const float n = tanhf(gin + r * (s2 + bhn));
        h_store32(hnew + (size_t)row * 512 + col, (1.0f - z) * n + z * hv);

        if (t + 1 < tc) {
            // Next step's gi BEFORE the barrier (touches only X/wih/accs_g).
            gi_compute(accs_g, X, wihH, wihL, t + 1, tid, rt, ct,
                       bir, biz, bin, gir, giz, gin);
            // R10-proven barrier: arrive+poll adjacent, tightly fenced.
            group_barrier(gf, ct, (unsigned)(t + 1));
        }
    }
}

// ---- Fallback: one step per launch; computes its own gi inline. ----
__global__ __launch_bounds__(256, 2) void gru_step_fb(
    const float* __restrict__ X,
    const unsigned short* __restrict__ wihH,
    const unsigned short* __restrict__ wihL,
    const unsigned short* __restrict__ whhH,
    const unsigned short* __restrict__ whhL,
    const float* __restrict__ bih,
    const float* __restrict__ bhh,
    const float* __restrict__ hold, float* __restrict__ hnew,
    const int step)
{
    __shared__ float accs_r[4 * 3 * 4 * 64];
    __shared__ float accs_g[4 * 3 * 4 * 64];
    const int tid = threadIdx.x;
    const int l = tid & 63, wv = tid >> 6;
    const int ct = blockIdx.x & 31;
    const int rt = blockIdx.x >> 5;
    const int col = ct * 16 + (l & 15);
    const int row = rt * 16 + ((l >> 4) << 2) + wv;
    const float bir = bih[col], biz = bih[512 + col], bin = bih[1024 + col];
    float gir, giz, gin;
    gi_compute(accs_g, X, wihH, wihL, step, tid, rt, ct, bir, biz, bin,
               gir, giz, gin);
    float s0, s1, s2;
    recur_compute(accs_r, whhH, whhL, hold, tid, rt, ct, s0, s1, s2);
    const float hv = h_load32(hold + (size_t)row * 512 + col);
    const float r = sigmoidf_(gir + s0 + bhh[col]);
    const float z = sigmoidf_(giz + s1 + bhh[512 + col]);
    const float n = tanhf(gin + r * (s2 + bhh[1024 + col]));
    h_store32(hnew + (size_t)row * 512 + col, (1.0f - z) * n + z * hv);
}

// ---- Phase 3 fp32 GEMM (exact; known-good) ----
template<bool TANH>
__global__ __launch_bounds__(256) void gemm_nt_bias(
    const float* __restrict__ A, const float* __restrict__ B,
    const float* __restrict__ bias, float* __restrict__ C,
    const int N, const int K)
{
    __shared__ float As[32][68];
    __shared__ float Bs[32][68];
    const int nb = blockIdx.x, mb = blockIdx.y;
    const int t  = threadIdx.x;
    const int tx = t & 15, ty = t >> 4;
    const int lr = t >> 3;
    const int lk = (t & 7) << 2;
    const float* pA = A + (size_t)(mb * 64 + lr) * K + lk;
    const float* pB = B + (size_t)(nb * 64 + lr) * K + lk;
    float acc[4][4];
#pragma unroll
    for (int i = 0; i < 4; ++i)
#pragma unroll
        for (int j = 0; j < 4; ++j) acc[i][j] = 0.0f;
    for (int kk = 0; kk < K; kk += 32) {
        const float4 a0 = *(const float4*)(pA + kk);
        const float4 a1 = *(const float4*)(pA + (size_t)32 * K + kk);
        const float4 b0 = *(const float4*)(pB + kk);
        const float4 b1 = *(const float4*)(pB + (size_t)32 * K + kk);
        __syncthreads();
        As[lk+0][lr] = a0.x; As[lk+1][lr] = a0.y; As[lk+2][lr] = a0.z; As[lk+3][lr] = a0.w;
        As[lk+0][lr+32] = a1.x; As[lk+1][lr+32] = a1.y; As[lk+2][lr+32] = a1.z; As[lk+3][lr+32] = a1.w;
        Bs[lk+0][lr] = b0.x; Bs[lk+1][lr] = b0.y; Bs[lk+2][lr] = b0.z; Bs[lk+3][lr] = b0.w;
        Bs[lk+0][lr+32] = b1.x; Bs[lk+1][lr+32] = b1.y; Bs[lk+2][lr+32] = b1.z; Bs[lk+3][lr+32] = b1.w;
        __syncthreads();
#pragma unroll
        for (int k = 0; k < 32; ++k) {
            const float4 av = *(const float4*)&As[k][ty << 2];
            const float4 bv = *(const float4*)&Bs[k][tx << 2];
            acc[0][0] += av.x * bv.x; acc[0][1] += av.x * bv.y; acc[0][2] += av.x * bv.z; acc[0][3] += av.x * bv.w;
            acc[1][0] += av.y * bv.x; acc[1][1] += av.y * bv.y; acc[1][2] += av.y * bv.z; acc[1][3] += av.y * bv.w;
            acc[2][0] += av.z * bv.x; acc[2][1] += av.z * bv.y; acc[2][2] += av.z * bv.z; acc[2][3] += av.z * bv.w;
            acc[3][0] += av.w * bv.x; acc[3][1] += av.w * bv.y; acc[3][2] += av.w * bv.z; acc[3][3] += av.w * bv.w;
        }
    }
    const int crow = mb * 64 + (ty << 2);
    const int ccol = nb * 64 + (tx << 2);
    const float4 bv = *(const float4*)(bias + ccol);
#pragma unroll
    for (int i = 0; i < 4; ++i) {
        float4 o;
        o.x = acc[i][0] + bv.x; o.y = acc[i][1] + bv.y;
        o.z = acc[i][2] + bv.z; o.w = acc[i][3] + bv.w;
        if (TANH) { o.x = tanhf(o.x); o.y = tanhf(o.y); o.z = tanhf(o.z); o.w = tanhf(o.w); }
        *(float4*)(C + (size_t)(crow + i) * N + ccol) = o;
    }
}

__global__ __launch_bounds__(256) void value_head(
    const float* __restrict__ out1, const float* __restrict__ W2,
    const float* __restrict__ b2, float* __restrict__ out)
{
    const int b = blockIdx.x, t = threadIdx.x;
    float p = out1[(size_t)b * 512 + t] * W2[t]
            + out1[(size_t)b * 512 + 256 + t] * W2[256 + t];
#pragma unroll
    for (int off = 32; off > 0; off >>= 1) p += __shfl_down(p, off, 64);
    __shared__ float ps[4];
    if ((t & 63) == 0) ps[t >> 6] = p;
    __syncthreads();
    if (t == 0) out[b] = tanhf(ps[0] + ps[1] + ps[2] + ps[3] + b2[0]);
}

extern "C" void kernel_launch(void* const* d_in, const int* in_sizes, int n_in,
                              void* d_out, int out_size, void* d_ws, size_t ws_size,
                              hipStream_t stream)
{
    (void)in_sizes; (void)n_in; (void)out_size; (void)ws_size;
    const float* input = (const float*)d_in[0];   // [256,256,512]
    const float* w_ih  = (const float*)d_in[1];   // [1536,512]
    const float* w_hh  = (const float*)d_in[2];   // [1536,512]
    const float* b_ih  = (const float*)d_in[3];   // [1536]
    const float* b_hh  = (const float*)d_in[4];   // [1536]
    const float* W1    = (const float*)d_in[5];   // [512,512]
    const float* b1    = (const float*)d_in[6];   // [512]
    const float* W2    = (const float*)d_in[7];   // [512]
    const float* b2    = (const float*)d_in[8];   // [1]
    float* out = (float*)d_out;
    float* ws  = (float*)d_ws;

    // ws layout in FLOAT SLOTS. One [1536,512] bf16 buffer = 786432 ushorts
    // = 1,572,864 B = 393,216 float slots.
    float* hA = ws;                                        // [0, 131072)
    float* hB = ws + 131072;                               // [131072, 262144)
    float* o1 = ws + 262144;                               // [262144, 393216)
    unsigned short* wihH = (unsigned short*)(ws + 393216); // [393216, 786432)
    unsigned short* wihL = (unsigned short*)(ws + 786432); // [786432, 1179648)
    unsigned short* whhH = (unsigned short*)(ws + 1179648);// [1179648, 1572864)
    unsigned short* whhL = (unsigned short*)(ws + 1572864);// [1572864, 1966080)
    unsigned* flags = (unsigned*)(ws + 1966080);           // 512 u32

    // Uniform state every launch/replay: h ping-pong AND flags zeroed.
    hipMemsetAsync(hA, 0, 262144 * sizeof(float), stream);    // hA + hB = 0
    hipMemsetAsync(flags, 0, 512 * sizeof(unsigned), stream); // barrier gen 0

    cast_split<<<768, 256, 0, stream>>>(w_ih, wihH, wihL, 196608);
    cast_split<<<768, 256, 0, stream>>>(w_hh, whhH, whhL, 196608);

    // Fused phase 2: all 256 steps + in-register gi, one coop launch.
    {
        const float* a_X = input;
        const unsigned short* a_ih = wihH; const unsigned short* a_il = wihL;
        const unsigned short* a_hh = whhH; const unsigned short* a_hl = whhL;
        const float* a_bi = b_ih; const float* a_bh = b_hh;
        float* a_hA = hA; float* a_hB = hB;
        unsigned* a_fl = flags;
        int a_tc = 256;
        void* args[] = {&a_X, &a_ih, &a_il, &a_hh, &a_hl, &a_bi, &a_bh,
                        &a_hA, &a_hB, &a_fl, &a_tc};
        hipError_t rc = hipLaunchCooperativeKernel(
            (const void*)gru_coop, dim3(512), dim3(256), args, 0, stream);
        if (rc != hipSuccess) {
            // Fallback: per-step launches (kernel boundary = grid barrier)
            for (int t = 0; t < 256; ++t) {
                const float* hold = (t & 1) ? hB : hA;
                float* hnew = (t & 1) ? hA : hB;
                gru_step_fb<<<dim3(512), 256, 0, stream>>>(
                    input, wihH, wihL, whhH, whhL, b_ih, b_hh, hold, hnew, t);
            }
        }
    }

    // Phase 3: final h is in hA (after 256 steps, even count).
    gemm_nt_bias<true><<<dim3(512 / 64, 256 / 64), 256, 0, stream>>>(
        hA, W1, b1, o1, 512, 512);
    value_head<<<256, 256, 0, stream>>>(o1, W2, b2, out);
}

// Round 13
// 3589.648 us; speedup vs baseline: 1.0085x; 1.0085x over previous
//
#include <hip/hip_runtime.h>
#include <hip/hip_bf16.h>

typedef __attribute__((ext_vector_type(8))) short short8v;   // 8 bf16 = 16 B
typedef __attribute__((ext_vector_type(4))) float f32x4;

union SV { short8v v; unsigned short u[8]; };
union FU { float f; unsigned u; };
union QF { unsigned long long q[4]; float4 v[2]; };

// Truncation split: x ~= hi + lo, residual <= 2^-16 |x|.
__device__ __forceinline__ void split2(float x, unsigned short& hi, unsigned short& lo) {
    FU a; a.f = x;
    hi = (unsigned short)(a.u >> 16);
    FU h; h.u = a.u & 0xffff0000u;
    FU r; r.f = x - h.f;              // exact
    lo = (unsigned short)(r.u >> 16);
}
__device__ __forceinline__ void split8(const float4 a0, const float4 a1, SV& h, SV& l) {
    split2(a0.x, h.u[0], l.u[0]); split2(a0.y, h.u[1], l.u[1]);
    split2(a0.z, h.u[2], l.u[2]); split2(a0.w, h.u[3], l.u[3]);
    split2(a1.x, h.u[4], l.u[4]); split2(a1.y, h.u[5], l.u[5]);
    split2(a1.z, h.u[6], l.u[6]); split2(a1.w, h.u[7], l.u[7]);
}
__device__ __forceinline__ float sigmoidf_(float x) {
    return 1.0f / (1.0f + __expf(-x));
}

// Agent-scope (LLC-coherent, L2-bypassing) h accessors — all cross-step h
// traffic, so no cache-maintenance fences are needed anywhere.
__device__ __forceinline__ unsigned long long h_load64(const float* p) {
    return __hip_atomic_load((const unsigned long long*)p,
                             __ATOMIC_RELAXED, __HIP_MEMORY_SCOPE_AGENT);
}
__device__ __forceinline__ float h_load32(const float* p) {
    FU u; u.u = __hip_atomic_load((const unsigned*)p,
                                  __ATOMIC_RELAXED, __HIP_MEMORY_SCOPE_AGENT);
    return u.f;
}
__device__ __forceinline__ void h_store32(float* p, float v) {
    FU u; u.f = v;
    __hip_atomic_store((unsigned*)p, u.u,
                       __ATOMIC_RELAXED, __HIP_MEMORY_SCOPE_AGENT);
}

// Per-rt-group barrier — VERBATIM the R9/R10/R12 replay-proven shape:
// arrive and poll adjacent, tightly fenced, NO work inside.
__device__ __forceinline__ void group_barrier(unsigned* gf, const int ct,
                                              const unsigned gen) {
    __builtin_amdgcn_s_waitcnt(0);
    __syncthreads();
    __atomic_signal_fence(__ATOMIC_SEQ_CST);
    if (threadIdx.x == 0)
        __hip_atomic_store(&gf[ct], gen,
                           __ATOMIC_RELAXED, __HIP_MEMORY_SCOPE_AGENT);
    if (threadIdx.x < 16) {
        const unsigned long long* f64 = (const unsigned long long*)gf;
        for (;;) {
            unsigned long long v = __hip_atomic_load(
                &f64[threadIdx.x], __ATOMIC_RELAXED, __HIP_MEMORY_SCOPE_AGENT);
            if (((unsigned)v >= gen) && ((unsigned)(v >> 32) >= gen)) break;
            __builtin_amdgcn_s_sleep(1);
        }
    }
    __atomic_signal_fence(__ATOMIC_SEQ_CST);
    __syncthreads();
}

// ---- split-cast weights f32 -> (hi, lo) bf16, once ----
__global__ __launch_bounds__(256) void cast_split(
    const float* __restrict__ in, unsigned short* __restrict__ hi,
    unsigned short* __restrict__ lo, int n4)
{
    int i = blockIdx.x * 256 + threadIdx.x;
    if (i < n4) {
        float4 v = ((const float4*)in)[i];
        ushort4 h, l;
        split2(v.x, h.x, l.x); split2(v.y, h.y, l.y);
        split2(v.z, h.z, l.z); split2(v.w, h.w, l.w);
        ((ushort4*)hi)[i] = h;
        ((ushort4*)lo)[i] = l;
    }
}

// ---- gi slice (prologue + fallback): g{r,z,n} for this thread's element.
__device__ __forceinline__ void gi_compute(
    float* accs_g,                             // LDS [4][3][4][64]
    const float* __restrict__ X,               // [S*256, 512] fp32
    const unsigned short* __restrict__ wihH,
    const unsigned short* __restrict__ wihL,
    const int step, const int tid, const int rt, const int ct,
    const float bir, const float biz, const float bin,
    float& gr, float& gz, float& gn)
{
    const int l = tid & 63, wv = tid >> 6;
    const int arow = l & 15, ksl = l >> 4, kbase = wv * 128;
    const int c0 = ct * 16, row0 = rt * 16;
    const float* xa = X + ((size_t)step * 256 + row0 + arow) * 512 + kbase + ksl * 8;
    f32x4 acc[3] = {};
#pragma unroll
    for (int j = 0; j < 4; ++j) {
        const float4 x0 = *(const float4*)(xa + j * 32);
        const float4 x1 = *(const float4*)(xa + j * 32 + 4);
        SV ah, al;
        split8(x0, x1, ah, al);
        const int ko = kbase + j * 32 + ksl * 8;
#pragma unroll
        for (int g = 0; g < 3; ++g) {
            const size_t wo = (size_t)((g << 9) + c0 + arow) * 512 + ko;
            const short8v bh = *(const short8v*)(wihH + wo);
            const short8v bl = *(const short8v*)(wihL + wo);
            acc[g] = __builtin_amdgcn_mfma_f32_16x16x32_bf16(ah.v, bh, acc[g], 0, 0, 0);
            acc[g] = __builtin_amdgcn_mfma_f32_16x16x32_bf16(ah.v, bl, acc[g], 0, 0, 0);
            acc[g] = __builtin_amdgcn_mfma_f32_16x16x32_bf16(al.v, bh, acc[g], 0, 0, 0);
        }
    }
#pragma unroll
    for (int g = 0; g < 3; ++g)
#pragma unroll
        for (int rg = 0; rg < 4; ++rg)
            accs_g[((wv * 3 + g) * 4 + rg) * 64 + l] = acc[g][rg];
    __syncthreads();
    gr = accs_g[((0 * 3 + 0) * 4 + wv) * 64 + l]
       + accs_g[((1 * 3 + 0) * 4 + wv) * 64 + l]
       + accs_g[((2 * 3 + 0) * 4 + wv) * 64 + l]
       + accs_g[((3 * 3 + 0) * 4 + wv) * 64 + l] + bir;
    gz = accs_g[((0 * 3 + 1) * 4 + wv) * 64 + l]
       + accs_g[((1 * 3 + 1) * 4 + wv) * 64 + l]
       + accs_g[((2 * 3 + 1) * 4 + wv) * 64 + l]
       + accs_g[((3 * 3 + 1) * 4 + wv) * 64 + l] + biz;
    gn = accs_g[((0 * 3 + 2) * 4 + wv) * 64 + l]
       + accs_g[((1 * 3 + 2) * 4 + wv) * 64 + l]
       + accs_g[((2 * 3 + 2) * 4 + wv) * 64 + l]
       + accs_g[((3 * 3 + 2) * 4 + wv) * 64 + l] + bin;
}

// ---- recurrent slice (fallback only) ----
__device__ __forceinline__ void recur_compute(
    float* accs_r,
    const unsigned short* __restrict__ whhH,
    const unsigned short* __restrict__ whhL,
    const float* __restrict__ hold,
    const int tid, const int rt, const int ct,
    float& s0, float& s1, float& s2)
{
    const int l = tid & 63, wv = tid >> 6;
    const int arow = l & 15, ksl = l >> 4, kbase = wv * 128;
    const int c0 = ct * 16, row0 = rt * 16;
    unsigned long long a_raw[4][4];
    const float* ha = hold + (size_t)(row0 + arow) * 512 + kbase + ksl * 8;
#pragma unroll
    for (int j = 0; j < 4; ++j)
#pragma unroll
        for (int q = 0; q < 4; ++q)
            a_raw[j][q] = h_load64(ha + j * 32 + q * 2);
    f32x4 acc[3] = {};
#pragma unroll
    for (int j = 0; j < 4; ++j) {
        QF buf;
#pragma unroll
        for (int q = 0; q < 4; ++q) buf.q[q] = a_raw[j][q];
        SV ah, al;
        split8(buf.v[0], buf.v[1], ah, al);
        const int ko = kbase + j * 32 + ksl * 8;
#pragma unroll
        for (int g = 0; g < 3; ++g) {
            const size_t wo = (size_t)((g << 9) + c0 + arow) * 512 + ko;
            const short8v bh = *(const short8v*)(whhH + wo);
            const short8v bl = *(const short8v*)(whhL + wo);
            acc[g] = __builtin_amdgcn_mfma_f32_16x16x32_bf16(ah.v, bh, acc[g], 0, 0, 0);
            acc[g] = __builtin_amdgcn_mfma_f32_16x16x32_bf16(ah.v, bl, acc[g], 0, 0, 0);
            acc[g] = __builtin_amdgcn_mfma_f32_16x16x32_bf16(al.v, bh, acc[g], 0, 0, 0);
        }
    }
#pragma unroll
    for (int g = 0; g < 3; ++g)
#pragma unroll
        for (int rg = 0; rg < 4; ++rg)
            accs_r[((wv * 3 + g) * 4 + rg) * 64 + l] = acc[g][rg];
    __syncthreads();
    s0 = accs_r[((0 * 3 + 0) * 4 + wv) * 64 + l]
       + accs_r[((1 * 3 + 0) * 4 + wv) * 64 + l]
       + accs_r[((2 * 3 + 0) * 4 + wv) * 64 + l]
       + accs_r[((3 * 3 + 0) * 4 + wv) * 64 + l];
    s1 = accs_r[((0 * 3 + 1) * 4 + wv) * 64 + l]
       + accs_r[((1 * 3 + 1) * 4 + wv) * 64 + l]
       + accs_r[((2 * 3 + 1) * 4 + wv) * 64 + l]
       + accs_r[((3 * 3 + 1) * 4 + wv) * 64 + l];
    s2 = accs_r[((0 * 3 + 2) * 4 + wv) * 64 + l]
       + accs_r[((1 * 3 + 2) * 4 + wv) * 64 + l]
       + accs_r[((2 * 3 + 2) * 4 + wv) * 64 + l]
       + accs_r[((3 * 3 + 2) * 4 + wv) * 64 + l];
}

// ---- Fused persistent kernel. Per step:
//   1. issue X[t+1] loads (hide LLC latency under recur)
//   2. issue h loads (LLC atomics) + hv
//   3. recur MFMAs   4. gi MFMAs (X in regs, w_ih L2-hot)
//   5. write BOTH partial sets to disjoint LDS, ONE __syncthreads
//   6. read recur sums -> epilogue -> h store
//   7. read gi sums -> gir/giz/gin for next step
//   8. group_barrier (proven shape, nothing inside)
__global__ __launch_bounds__(256, 2) void gru_coop(
    const float* __restrict__ X,               // [256*256, 512] input
    const unsigned short* __restrict__ wihH,
    const unsigned short* __restrict__ wihL,
    const unsigned short* __restrict__ whhH,
    const unsigned short* __restrict__ whhL,
    const float* __restrict__ bih,
    const float* __restrict__ bhh,
    float* __restrict__ hA, float* __restrict__ hB,
    unsigned* __restrict__ flags,              // 16 groups x 32 u32
    const int tc)
{
    __shared__ float accs_r[4 * 3 * 4 * 64];   // 12 KB recurrent partials
    __shared__ float accs_g[4 * 3 * 4 * 64];   // 12 KB gi partials
    const int tid = threadIdx.x;
    const int l = tid & 63, wv = tid >> 6;
    const int ct = blockIdx.x & 31;
    const int rt = blockIdx.x >> 5;
    const int arow = l & 15, ksl = l >> 4, kbase = wv * 128;
    const int c0 = ct * 16, row0 = rt * 16;
    unsigned* gf = flags + rt * 32;

    const int col = c0 + arow;
    const int row = row0 + (ksl << 2) + wv;
    const float bir = bih[col], biz = bih[512 + col], bin = bih[1024 + col];
    const float bhr = bhh[col], bhz = bhh[512 + col], bhn = bhh[1024 + col];

    // Prologue: gi[0] (X-GEMM only).
    float gir, giz, gin;
    gi_compute(accs_g, X, wihH, wihL, 0, tid, rt, ct, bir, biz, bin,
               gir, giz, gin);
    __syncthreads();   // prologue accs_g reads done before step-0 writes

    for (int t = 0; t < tc; ++t) {
        const float* hold = (t & 1) ? hB : hA;
        float* hnew = (t & 1) ? hA : hB;
        const bool last = (t + 1 >= tc);

        // 1. X prefetch for t+1 (plain loads; latency hides under recur).
        float4 xp[8];
        if (!last) {
            const float* xa = X + ((size_t)(t + 1) * 256 + row0 + arow) * 512
                            + kbase + ksl * 8;
#pragma unroll
            for (int j = 0; j < 4; ++j) {
                xp[2 * j]     = *(const float4*)(xa + j * 32);
                xp[2 * j + 1] = *(const float4*)(xa + j * 32 + 4);
            }
        }

        // 2. h loads (LLC atomics) + hv for epilogue.
        unsigned long long a_raw[4][4];
        const float* ha = hold + (size_t)(row0 + arow) * 512 + kbase + ksl * 8;
#pragma unroll
        for (int j = 0; j < 4; ++j)
#pragma unroll
            for (int q = 0; q < 4; ++q)
                a_raw[j][q] = h_load64(ha + j * 32 + q * 2);
        const float hv = h_load32(hold + (size_t)row * 512 + col);

        // 3. recur MFMAs.
        f32x4 racc[3] = {};
#pragma unroll
        for (int j = 0; j < 4; ++j) {
            QF buf;
#pragma unroll
            for (int q = 0; q < 4; ++q) buf.q[q] = a_raw[j][q];
            SV ah, al;
            split8(buf.v[0], buf.v[1], ah, al);
            const int ko = kbase + j * 32 + ksl * 8;
#pragma unroll
            for (int g = 0; g < 3; ++g) {
                const size_t wo = (size_t)((g << 9) + c0 + arow) * 512 + ko;
                const short8v bh = *(const short8v*)(whhH + wo);
                const short8v bl = *(const short8v*)(whhL + wo);
                racc[g] = __builtin_amdgcn_mfma_f32_16x16x32_bf16(ah.v, bh, racc[g], 0, 0, 0);
                racc[g] = __builtin_amdgcn_mfma_f32_16x16x32_bf16(ah.v, bl, racc[g], 0, 0, 0);
                racc[g] = __builtin_amdgcn_mfma_f32_16x16x32_bf16(al.v, bh, racc[g], 0, 0, 0);
            }
        }

        // 4. gi MFMAs for t+1 (X already in registers).
        f32x4 gacc[3] = {};
        if (!last) {
#pragma unroll
            for (int j = 0; j < 4; ++j) {
                SV ah, al;
                split8(xp[2 * j], xp[2 * j + 1], ah, al);
                const int ko = kbase + j * 32 + ksl * 8;
#pragma unroll
                for (int g = 0; g < 3; ++g) {
                    const size_t wo = (size_t)((g << 9) + c0 + arow) * 512 + ko;
                    const short8v bh = *(const short8v*)(wihH + wo);
                    const short8v bl = *(const short8v*)(wihL + wo);
                    gacc[g] = __builtin_amdgcn_mfma_f32_16x16x32_bf16(ah.v, bh, gacc[g], 0, 0, 0);
                    gacc[g] = __builtin_amdgcn_mfma_f32_16x16x32_bf16(ah.v, bl, gacc[g], 0, 0, 0);
                    gacc[g] = __builtin_amdgcn_mfma_f32_16x16x32_bf16(al.v, bh, gacc[g], 0, 0, 0);
                }
            }
        }

        // 5. Write both partial sets; single sync.
#pragma unroll
        for (int g = 0; g < 3; ++g)
#pragma unroll
            for (int rg = 0; rg < 4; ++rg)
                accs_r[((wv * 3 + g) * 4 + rg) * 64 + l] = racc[g][rg];
        if (!last) {
#pragma unroll
            for (int g = 0; g < 3; ++g)
#pragma unroll
                for (int rg = 0; rg < 4; ++rg)
                    accs_g[((wv * 3 + g) * 4 + rg) * 64 + l] = gacc[g][rg];
        }
        __syncthreads();

        // 6. Recur sums -> epilogue -> h store.
        const float s0 = accs_r[((0 * 3 + 0) * 4 + wv) * 64 + l]
                       + accs_r[((1 * 3 + 0) * 4 + wv) * 64 + l]
                       + accs_r[((2 * 3 + 0) * 4 + wv) * 64 + l]
                       + accs_r[((3 * 3 + 0) * 4 + wv) * 64 + l];
        const float s1 = accs_r[((0 * 3 + 1) * 4 + wv) * 64 + l]
                       + accs_r[((1 * 3 + 1) * 4 + wv) * 64 + l]
                       + accs_r[((2 * 3 + 1) * 4 + wv) * 64 + l]
                       + accs_r[((3 * 3 + 1) * 4 + wv) * 64 + l];
        const float s2 = accs_r[((0 * 3 + 2) * 4 + wv) * 64 + l]
                       + accs_r[((1 * 3 + 2) * 4 + wv) * 64 + l]
                       + accs_r[((2 * 3 + 2) * 4 + wv) * 64 + l]
                       + accs_r[((3 * 3 + 2) * 4 + wv) * 64 + l];
        const float r = sigmoidf_(gir + s0 + bhr);
        const float z = sigmoidf_(giz + s1 + bhz);
        const float n = tanhf(gin + r * (s2 + bhn));
        h_store32(hnew + (size_t)row * 512 + col, (1.0f - z) * n + z * hv);

        if (!last) {
            // 7. gi sums for next step.
            gir = accs_g[((0 * 3 + 0) * 4 + wv) * 64 + l]
                + accs_g[((1 * 3 + 0) * 4 + wv) * 64 + l]
                + accs_g[((2 * 3 + 0) * 4 + wv) * 64 + l]
                + accs_g[((3 * 3 + 0) * 4 + wv) * 64 + l] + bir;
            giz = accs_g[((0 * 3 + 1) * 4 + wv) * 64 + l]
                + accs_g[((1 * 3 + 1) * 4 + wv) * 64 + l]
                + accs_g[((2 * 3 + 1) * 4 + wv) * 64 + l]
                + accs_g[((3 * 3 + 1) * 4 + wv) * 64 + l] + biz;
            gin = accs_g[((0 * 3 + 2) * 4 + wv) * 64 + l]
                + accs_g[((1 * 3 + 2) * 4 + wv) * 64 + l]
                + accs_g[((2 * 3 + 2) * 4 + wv) * 64 + l]
                + accs_g[((3 * 3 + 2) * 4 + wv) * 64 + l] + bin;
            // 8. Proven barrier (also closes the LDS WAR for the next step).
            group_barrier(gf, ct, (unsigned)(t + 1));
        }
    }
}

// ---- Fallback: one step per launch; computes its own gi inline. ----
__global__ __launch_bounds__(256, 2) void gru_step_fb(
    const float* __restrict__ X,
    const unsigned short* __restrict__ wihH,
    const unsigned short* __restrict__ wihL,
    const unsigned short* __restrict__ whhH,
    const unsigned short* __restrict__ whhL,
    const float* __restrict__ bih,
    const float* __restrict__ bhh,
    const float* __restrict__ hold, float* __restrict__ hnew,
    const int step)
{
    __shared__ float accs_r[4 * 3 * 4 * 64];
    __shared__ float accs_g[4 * 3 * 4 * 64];
    const int tid = threadIdx.x;
    const int l = tid & 63, wv = tid >> 6;
    const int ct = blockIdx.x & 31;
    const int rt = blockIdx.x >> 5;
    const int col = ct * 16 + (l & 15);
    const int row = rt * 16 + ((l >> 4) << 2) + wv;
    const float bir = bih[col], biz = bih[512 + col], bin = bih[1024 + col];
    float gir, giz, gin;
    gi_compute(accs_g, X, wihH, wihL, step, tid, rt, ct, bir, biz, bin,
               gir, giz, gin);
    float s0, s1, s2;
    recur_compute(accs_r, whhH, whhL, hold, tid, rt, ct, s0, s1, s2);
    const float hv = h_load32(hold + (size_t)row * 512 + col);
    const float r = sigmoidf_(gir + s0 + bhh[col]);
    const float z = sigmoidf_(giz + s1 + bhh[512 + col]);
    const float n = tanhf(gin + r * (s2 + bhh[1024 + col]));
    h_store32(hnew + (size_t)row * 512 + col, (1.0f - z) * n + z * hv);
}

// ---- Phase 3 fp32 GEMM (exact; known-good) ----
template<bool TANH>
__global__ __launch_bounds__(256) void gemm_nt_bias(
    const float* __restrict__ A, const float* __restrict__ B,
    const float* __restrict__ bias, float* __restrict__ C,
    const int N, const int K)
{
    __shared__ float As[32][68];
    __shared__ float Bs[32][68];
    const int nb = blockIdx.x, mb = blockIdx.y;
    const int t  = threadIdx.x;
    const int tx = t & 15, ty = t >> 4;
    const int lr = t >> 3;
    const int lk = (t & 7) << 2;
    const float* pA = A + (size_t)(mb * 64 + lr) * K + lk;
    const float* pB = B + (size_t)(nb * 64 + lr) * K + lk;
    float acc[4][4];
#pragma unroll
    for (int i = 0; i < 4; ++i)
#pragma unroll
        for (int j = 0; j < 4; ++j) acc[i][j] = 0.0f;
    for (int kk = 0; kk < K; kk += 32) {
        const float4 a0 = *(const float4*)(pA + kk);
        const float4 a1 = *(const float4*)(pA + (size_t)32 * K + kk);
        const float4 b0 = *(const float4*)(pB + kk);
        const float4 b1 = *(const float4*)(pB + (size_t)32 * K + kk);
        __syncthreads();
        As[lk+0][lr] = a0.x; As[lk+1][lr] = a0.y; As[lk+2][lr] = a0.z; As[lk+3][lr] = a0.w;
        As[lk+0][lr+32] = a1.x; As[lk+1][lr+32] = a1.y; As[lk+2][lr+32] = a1.z; As[lk+3][lr+32] = a1.w;
        Bs[lk+0][lr] = b0.x; Bs[lk+1][lr] = b0.y; Bs[lk+2][lr] = b0.z; Bs[lk+3][lr] = b0.w;
        Bs[lk+0][lr+32] = b1.x; Bs[lk+1][lr+32] = b1.y; Bs[lk+2][lr+32] = b1.z; Bs[lk+3][lr+32] = b1.w;
        __syncthreads();
#pragma unroll
        for (int k = 0; k < 32; ++k) {
            const float4 av = *(const float4*)&As[k][ty << 2];
            const float4 bv = *(const float4*)&Bs[k][tx << 2];
            acc[0][0] += av.x * bv.x; acc[0][1] += av.x * bv.y; acc[0][2] += av.x * bv.z; acc[0][3] += av.x * bv.w;
            acc[1][0] += av.y * bv.x; acc[1][1] += av.y * bv.y; acc[1][2] += av.y * bv.z; acc[1][3] += av.y * bv.w;
            acc[2][0] += av.z * bv.x; acc[2][1] += av.z * bv.y; acc[2][2] += av.z * bv.z; acc[2][3] += av.z * bv.w;
            acc[3][0] += av.w * bv.x; acc[3][1] += av.w * bv.y; acc[3][2] += av.w * bv.z; acc[3][3] += av.w * bv.w;
        }
    }
    const int crow = mb * 64 + (ty << 2);
    const int ccol = nb * 64 + (tx << 2);
    const float4 bv = *(const float4*)(bias + ccol);
#pragma unroll
    for (int i = 0; i < 4; ++i) {
        float4 o;
        o.x = acc[i][0] + bv.x; o.y = acc[i][1] + bv.y;
        o.z = acc[i][2] + bv.z; o.w = acc[i][3] + bv.w;
        if (TANH) { o.x = tanhf(o.x); o.y = tanhf(o.y); o.z = tanhf(o.z); o.w = tanhf(o.w); }
        *(float4*)(C + (size_t)(crow + i) * N + ccol) = o;
    }
}

__global__ __launch_bounds__(256) void value_head(
    const float* __restrict__ out1, const float* __restrict__ W2,
    const float* __restrict__ b2, float* __restrict__ out)
{
    const int b = blockIdx.x, t = threadIdx.x;
    float p = out1[(size_t)b * 512 + t] * W2[t]
            + out1[(size_t)b * 512 + 256 + t] * W2[256 + t];
#pragma unroll
    for (int off = 32; off > 0; off >>= 1) p += __shfl_down(p, off, 64);
    __shared__ float ps[4];
    if ((t & 63) == 0) ps[t >> 6] = p;
    __syncthreads();
    if (t == 0) out[b] = tanhf(ps[0] + ps[1] + ps[2] + ps[3] + b2[0]);
}

extern "C" void kernel_launch(void* const* d_in, const int* in_sizes, int n_in,
                              void* d_out, int out_size, void* d_ws, size_t ws_size,
                              hipStream_t stream)
{
    (void)in_sizes; (void)n_in; (void)out_size; (void)ws_size;
    const float* input = (const float*)d_in[0];   // [256,256,512]
    const float* w_ih  = (const float*)d_in[1];   // [1536,512]
    const float* w_hh  = (const float*)d_in[2];   // [1536,512]
    const float* b_ih  = (const float*)d_in[3];   // [1536]
    const float* b_hh  = (const float*)d_in[4];   // [1536]
    const float* W1    = (const float*)d_in[5];   // [512,512]
    const float* b1    = (const float*)d_in[6];   // [512]
    const float* W2    = (const float*)d_in[7];   // [512]
    const float* b2    = (const float*)d_in[8];   // [1]
    float* out = (float*)d_out;
    float* ws  = (float*)d_ws;

    // ws layout in FLOAT SLOTS. One [1536,512] bf16 buffer = 786432 ushorts
    // = 1,572,864 B = 393,216 float slots.
    float* hA = ws;                                        // [0, 131072)
    float* hB = ws + 131072;                               // [131072, 262144)
    float* o1 = ws + 262144;                               // [262144, 393216)
    unsigned short* wihH = (unsigned short*)(ws + 393216); // [393216, 786432)
    unsigned short* wihL = (unsigned short*)(ws + 786432); // [786432, 1179648)
    unsigned short* whhH = (unsigned short*)(ws + 1179648);// [1179648, 1572864)
    unsigned short* whhL = (unsigned short*)(ws + 1572864);// [1572864, 1966080)
    unsigned* flags = (unsigned*)(ws + 1966080);           // 512 u32

    // Uniform state every launch/replay: h ping-pong AND flags zeroed.
    hipMemsetAsync(hA, 0, 262144 * sizeof(float), stream);    // hA + hB = 0
    hipMemsetAsync(flags, 0, 512 * sizeof(unsigned), stream); // barrier gen 0

    cast_split<<<768, 256, 0, stream>>>(w_ih, wihH, wihL, 196608);
    cast_split<<<768, 256, 0, stream>>>(w_hh, whhH, whhL, 196608);

    // Fused phase 2: all 256 steps + in-register gi, one coop launch.
    {
        const float* a_X = input;
        const unsigned short* a_ih = wihH; const unsigned short* a_il = wihL;
        const unsigned short* a_hh = whhH; const unsigned short* a_hl = whhL;
        const float* a_bi = b_ih; const float* a_bh = b_hh;
        float* a_hA = hA; float* a_hB = hB;
        unsigned* a_fl = flags;
        int a_tc = 256;
        void* args[] = {&a_X, &a_ih, &a_il, &a_hh, &a_hl, &a_bi, &a_bh,
                        &a_hA, &a_hB, &a_fl, &a_tc};
        hipError_t rc = hipLaunchCooperativeKernel(
            (const void*)gru_coop, dim3(512), dim3(256), args, 0, stream);
        if (rc != hipSuccess) {
            // Fallback: per-step launches (kernel boundary = grid barrier)
            for (int t = 0; t < 256; ++t) {
                const float* hold = (t & 1) ? hB : hA;
                float* hnew = (t & 1) ? hA : hB;
                gru_step_fb<<<dim3(512), 256, 0, stream>>>(
                    input, wihH, wihL, whhH, whhL, b_ih, b_hh, hold, hnew, t);
            }
        }
    }

    // Phase 3: final h is in hA (after 256 steps, even count).
    gemm_nt_bias<true><<<dim3(512 / 64, 256 / 64), 256, 0, stream>>>(
        hA, W1, b1, o1, 512, 512);
    value_head<<<256, 256, 0, stream>>>(o1, W2, b2, out);
}

// Round 14
// 2451.823 us; speedup vs baseline: 1.4765x; 1.4641x over previous
//
#include <hip/hip_runtime.h>
#include <hip/hip_bf16.h>

typedef __attribute__((ext_vector_type(8))) short short8v;   // 8 bf16 = 16 B
typedef __attribute__((ext_vector_type(4))) float f32x4;

union SV { short8v v; unsigned short u[8]; };
union FU { float f; unsigned u; };
union QF { unsigned long long q[4]; float4 v[2]; };

// Truncation split: x ~= hi + lo, residual <= 2^-16 |x|.
__device__ __forceinline__ void split2(float x, unsigned short& hi, unsigned short& lo) {
    FU a; a.f = x;
    hi = (unsigned short)(a.u >> 16);
    FU h; h.u = a.u & 0xffff0000u;
    FU r; r.f = x - h.f;              // exact
    lo = (unsigned short)(r.u >> 16);
}
__device__ __forceinline__ void split8(const float4 a0, const float4 a1, SV& h, SV& l) {
    split2(a0.x, h.u[0], l.u[0]); split2(a0.y, h.u[1], l.u[1]);
    split2(a0.z, h.u[2], l.u[2]); split2(a0.w, h.u[3], l.u[3]);
    split2(a1.x, h.u[4], l.u[4]); split2(a1.y, h.u[5], l.u[5]);
    split2(a1.z, h.u[6], l.u[6]); split2(a1.w, h.u[7], l.u[7]);
}
__device__ __forceinline__ float sigmoidf_(float x) {
    return 1.0f / (1.0f + __expf(-x));
}

// Agent-scope (LLC-coherent, L2-bypassing) h accessors — all cross-step h
// traffic, so no cache-maintenance fences are needed anywhere.
__device__ __forceinline__ unsigned long long h_load64(const float* p) {
    return __hip_atomic_load((const unsigned long long*)p,
                             __ATOMIC_RELAXED, __HIP_MEMORY_SCOPE_AGENT);
}
__device__ __forceinline__ float h_load32(const float* p) {
    FU u; u.u = __hip_atomic_load((const unsigned*)p,
                                  __ATOMIC_RELAXED, __HIP_MEMORY_SCOPE_AGENT);
    return u.f;
}
__device__ __forceinline__ void h_store32(float* p, float v) {
    FU u; u.f = v;
    __hip_atomic_store((unsigned*)p, u.u,
                       __ATOMIC_RELAXED, __HIP_MEMORY_SCOPE_AGENT);
}

// Per-rt-group barrier — VERBATIM the R9/R10/R12 replay-proven shape:
// arrive and poll adjacent, tightly fenced, NO work inside.
__device__ __forceinline__ void group_barrier(unsigned* gf, const int ct,
                                              const unsigned gen) {
    __builtin_amdgcn_s_waitcnt(0);
    __syncthreads();
    __atomic_signal_fence(__ATOMIC_SEQ_CST);
    if (threadIdx.x == 0)
        __hip_atomic_store(&gf[ct], gen,
                           __ATOMIC_RELAXED, __HIP_MEMORY_SCOPE_AGENT);
    if (threadIdx.x < 16) {
        const unsigned long long* f64 = (const unsigned long long*)gf;
        for (;;) {
            unsigned long long v = __hip_atomic_load(
                &f64[threadIdx.x], __ATOMIC_RELAXED, __HIP_MEMORY_SCOPE_AGENT);
            if (((unsigned)v >= gen) && ((unsigned)(v >> 32) >= gen)) break;
            __builtin_amdgcn_s_sleep(1);
        }
    }
    __atomic_signal_fence(__ATOMIC_SEQ_CST);
    __syncthreads();
}

// ---- split-cast weights f32 -> (hi, lo) bf16, once ----
__global__ __launch_bounds__(256) void cast_split(
    const float* __restrict__ in, unsigned short* __restrict__ hi,
    unsigned short* __restrict__ lo, int n4)
{
    int i = blockIdx.x * 256 + threadIdx.x;
    if (i < n4) {
        float4 v = ((const float4*)in)[i];
        ushort4 h, l;
        split2(v.x, h.x, l.x); split2(v.y, h.y, l.y);
        split2(v.z, h.z, l.z); split2(v.w, h.w, l.w);
        ((ushort4*)hi)[i] = h;
        ((ushort4*)lo)[i] = l;
    }
}

// ---- Phase 1: gi = X @ w_ih^T + b_ih. Split-bf16 MFMA (3 products). ----
// 128x128 tile amortizes w_ih reads over 128 rows (the reason phase-split
// beats fusion: fused per-16-row blocks paid 8x this weight traffic).
__global__ __launch_bounds__(256, 2) void gemm_gi_mfma(
    const float* __restrict__ A,            // [M,512] fp32
    const unsigned short* __restrict__ Bh,  // [1536,512] bf16 hi
    const unsigned short* __restrict__ Bl,  // [1536,512] bf16 lo
    const float* __restrict__ bias,         // [1536]
    float* __restrict__ C)                  // [M,1536]
{
    __shared__ __attribute__((aligned(16))) unsigned char lds[65536];
    const int t = threadIdx.x;
    const int l = t & 63, w = t >> 6;
    const int nb = blockIdx.x, mb = blockIdx.y;
    const int p = t & 7;
    const int rbase = t >> 3;
    f32x4 acc[4][4] = {};

    for (int kk = 0; kk < 512; kk += 64) {
#pragma unroll
        for (int i = 0; i < 4; ++i) {
            const int r = i * 32 + rbase;
            const int q = p ^ (r & 7);
            const float* ga = A + (size_t)(mb * 128 + r) * 512 + kk + q * 8;
            SV ah, al;
            split8(*(const float4*)ga, *(const float4*)(ga + 4), ah, al);
            const int o = r * 128 + p * 16;
            *(short8v*)&lds[o] = ah.v;
            *(short8v*)&lds[16384 + o] = al.v;
            const size_t gb = (size_t)(nb * 128 + r) * 512 + kk + q * 8;
            *(short8v*)&lds[32768 + o] = *(const short8v*)(Bh + gb);
            *(short8v*)&lds[49152 + o] = *(const short8v*)(Bl + gb);
        }
        __syncthreads();
        const int mr0 = (w >> 1) * 64, nc0 = (w & 1) * 64;
#pragma unroll
        for (int kk2 = 0; kk2 < 2; ++kk2) {
            const int kap = kk2 * 4 + (l >> 4);
            short8v ah[4], al[4], bh[4], bl[4];
#pragma unroll
            for (int i = 0; i < 4; ++i) {
                const int row = mr0 + i * 16 + (l & 15);
                const int off = row * 128 + ((kap ^ (row & 7)) * 16);
                ah[i] = *(const short8v*)&lds[off];
                al[i] = *(const short8v*)&lds[16384 + off];
            }
#pragma unroll
            for (int j = 0; j < 4; ++j) {
                const int bn = nc0 + j * 16 + (l & 15);
                const int off = bn * 128 + ((kap ^ (bn & 7)) * 16);
                bh[j] = *(const short8v*)&lds[32768 + off];
                bl[j] = *(const short8v*)&lds[49152 + off];
            }
#pragma unroll
            for (int i = 0; i < 4; ++i)
#pragma unroll
                for (int j = 0; j < 4; ++j) {
                    acc[i][j] = __builtin_amdgcn_mfma_f32_16x16x32_bf16(ah[i], bh[j], acc[i][j], 0, 0, 0);
                    acc[i][j] = __builtin_amdgcn_mfma_f32_16x16x32_bf16(ah[i], bl[j], acc[i][j], 0, 0, 0);
                    acc[i][j] = __builtin_amdgcn_mfma_f32_16x16x32_bf16(al[i], bh[j], acc[i][j], 0, 0, 0);
                }
        }
        __syncthreads();
    }
    const int mr0 = (w >> 1) * 64, nc0 = (w & 1) * 64;
#pragma unroll
    for (int j = 0; j < 4; ++j) {
        const int col = nb * 128 + nc0 + j * 16 + (l & 15);
        const float bv = bias[col];
#pragma unroll
        for (int i = 0; i < 4; ++i) {
            const int row0 = mb * 128 + mr0 + i * 16 + (l >> 4) * 4;
#pragma unroll
            for (int rg = 0; rg < 4; ++rg)
                C[(size_t)(row0 + rg) * 1536 + col] = acc[i][j][rg] + bv;
        }
    }
}

// ---- Phase 2: R10 recur-only persistent kernel + w_hh REGISTER RESIDENCY.
// Each block computes the same (rt,ct) tile for all 256 steps, so its w_hh
// B-fragments (4 windows x 3 gates x hi/lo = 24 b128 = 96 VGPRs) are
// loop-invariant: load once, reuse 256x. Saves 96 KB/block/step of L2 reads
// (~1.4 us/step per CU in R10) + per-step address VALU. Arithmetic order is
// bit-identical to R10.
__global__ __launch_bounds__(256, 2) void gru_coop(
    const float* __restrict__ gi,              // [tc,256,1536] chunk base
    const unsigned short* __restrict__ whhH,
    const unsigned short* __restrict__ whhL,
    const float* __restrict__ bhh,
    float* __restrict__ hA, float* __restrict__ hB,
    unsigned* __restrict__ flags,              // 16 groups x 32 u32
    const int t0, const int tc)
{
    __shared__ float accs_f[4 * 3 * 4 * 64];   // 12 KB
    const int tid = threadIdx.x;
    const int l = tid & 63, wv = tid >> 6;
    const int ct = blockIdx.x & 31;
    const int rt = blockIdx.x >> 5;
    const int arow = l & 15, ksl = l >> 4, kbase = wv * 128;
    const int c0 = ct * 16, row0 = rt * 16;
    unsigned* gf = flags + rt * 32;
    const int col = c0 + arow;
    const int row = row0 + (ksl << 2) + wv;
    const float bhr = bhh[col], bhz = bhh[512 + col], bhn = bhh[1024 + col];

    // Loop-invariant w_hh fragments -> registers (once).
    short8v wbh[4][3], wbl[4][3];
#pragma unroll
    for (int j = 0; j < 4; ++j) {
        const int ko = kbase + j * 32 + ksl * 8;
#pragma unroll
        for (int g = 0; g < 3; ++g) {
            const size_t wo = (size_t)((g << 9) + c0 + arow) * 512 + ko;
            wbh[j][g] = *(const short8v*)(whhH + wo);
            wbl[j][g] = *(const short8v*)(whhL + wo);
        }
    }

    for (int s = 0; s < tc; ++s) {
        const int t = t0 + s;
        const float* hold = (t & 1) ? hB : hA;
        float* hnew = (t & 1) ? hA : hB;
        const float* gi_s = gi + (size_t)s * (256 * 1536);

        // h loads (LLC atomics) + hv, issued together.
        unsigned long long a_raw[4][4];
        const float* ha = hold + (size_t)(row0 + arow) * 512 + kbase + ksl * 8;
#pragma unroll
        for (int j = 0; j < 4; ++j)
#pragma unroll
            for (int q = 0; q < 4; ++q)
                a_raw[j][q] = h_load64(ha + j * 32 + q * 2);
        const float hv = h_load32(hold + (size_t)row * 512 + col);

        // recur MFMAs (w fragments from registers).
        f32x4 acc[3] = {};
#pragma unroll
        for (int j = 0; j < 4; ++j) {
            QF buf;
#pragma unroll
            for (int q = 0; q < 4; ++q) buf.q[q] = a_raw[j][q];
            SV ah, al;
            split8(buf.v[0], buf.v[1], ah, al);
#pragma unroll
            for (int g = 0; g < 3; ++g) {
                acc[g] = __builtin_amdgcn_mfma_f32_16x16x32_bf16(ah.v, wbh[j][g], acc[g], 0, 0, 0);
                acc[g] = __builtin_amdgcn_mfma_f32_16x16x32_bf16(ah.v, wbl[j][g], acc[g], 0, 0, 0);
                acc[g] = __builtin_amdgcn_mfma_f32_16x16x32_bf16(al.v, wbh[j][g], acc[g], 0, 0, 0);
            }
        }

        // Exchange partials across the 4 K-quarter waves.
#pragma unroll
        for (int g = 0; g < 3; ++g)
#pragma unroll
            for (int rg = 0; rg < 4; ++rg)
                accs_f[((wv * 3 + g) * 4 + rg) * 64 + l] = acc[g][rg];
        __syncthreads();

        const float s0 = accs_f[((0 * 3 + 0) * 4 + wv) * 64 + l]
                       + accs_f[((1 * 3 + 0) * 4 + wv) * 64 + l]
                       + accs_f[((2 * 3 + 0) * 4 + wv) * 64 + l]
                       + accs_f[((3 * 3 + 0) * 4 + wv) * 64 + l];
        const float s1 = accs_f[((0 * 3 + 1) * 4 + wv) * 64 + l]
                       + accs_f[((1 * 3 + 1) * 4 + wv) * 64 + l]
                       + accs_f[((2 * 3 + 1) * 4 + wv) * 64 + l]
                       + accs_f[((3 * 3 + 1) * 4 + wv) * 64 + l];
        const float s2 = accs_f[((0 * 3 + 2) * 4 + wv) * 64 + l]
                       + accs_f[((1 * 3 + 2) * 4 + wv) * 64 + l]
                       + accs_f[((2 * 3 + 2) * 4 + wv) * 64 + l]
                       + accs_f[((3 * 3 + 2) * 4 + wv) * 64 + l];
        const float* gp = gi_s + (size_t)row * 1536 + col;
        const float r = sigmoidf_(gp[0]    + s0 + bhr);
        const float z = sigmoidf_(gp[512]  + s1 + bhz);
        const float n = tanhf(gp[1024] + r * (s2 + bhn));
        h_store32(hnew + (size_t)row * 512 + col, (1.0f - z) * n + z * hv);

        if (s + 1 < tc)
            group_barrier(gf, ct, (unsigned)(t + 1));  // also covers LDS WAR
        else
            __syncthreads();                           // chunk-final WAR close
    }
}

// ---- Phase 2b tile body (fallback only; loads w per step) ----
__device__ __forceinline__ void gru_tile_body(
    float* accs_f,
    const float* __restrict__ gi_s,
    const unsigned short* __restrict__ whhH,
    const unsigned short* __restrict__ whhL,
    const float* __restrict__ bhh,
    const float* __restrict__ hold,
    float* __restrict__ hnew,
    const int tid, const int rt, const int ct)
{
    const int l = tid & 63, wv = tid >> 6;
    const int c0 = ct * 16, row0 = rt * 16;
    const int arow = l & 15;
    const int ksl  = l >> 4;
    const int kbase = wv * 128;

    unsigned long long a_raw[4][4];
    const float* ha = hold + (size_t)(row0 + arow) * 512 + kbase + ksl * 8;
#pragma unroll
    for (int j = 0; j < 4; ++j)
#pragma unroll
        for (int q = 0; q < 4; ++q)
            a_raw[j][q] = h_load64(ha + j * 32 + q * 2);

    f32x4 acc[3] = {};
#pragma unroll
    for (int j = 0; j < 4; ++j) {
        QF buf;
#pragma unroll
        for (int q = 0; q < 4; ++q) buf.q[q] = a_raw[j][q];
        SV ah, al;
        split8(buf.v[0], buf.v[1], ah, al);
        const int ko = kbase + j * 32 + ksl * 8;
#pragma unroll
        for (int g = 0; g < 3; ++g) {
            const size_t wo = (size_t)((g << 9) + c0 + arow) * 512 + ko;
            const short8v bh = *(const short8v*)(whhH + wo);
            const short8v bl = *(const short8v*)(whhL + wo);
            acc[g] = __builtin_amdgcn_mfma_f32_16x16x32_bf16(ah.v, bh, acc[g], 0, 0, 0);
            acc[g] = __builtin_amdgcn_mfma_f32_16x16x32_bf16(ah.v, bl, acc[g], 0, 0, 0);
            acc[g] = __builtin_amdgcn_mfma_f32_16x16x32_bf16(al.v, bh, acc[g], 0, 0, 0);
        }
    }
#pragma unroll
    for (int g = 0; g < 3; ++g)
#pragma unroll
        for (int rg = 0; rg < 4; ++rg)
            accs_f[((wv * 3 + g) * 4 + rg) * 64 + l] = acc[g][rg];
    __syncthreads();

    const int col = c0 + arow;
    const int row = row0 + (ksl << 2) + wv;
    float s0 = accs_f[((0 * 3 + 0) * 4 + wv) * 64 + l]
             + accs_f[((1 * 3 + 0) * 4 + wv) * 64 + l]
             + accs_f[((2 * 3 + 0) * 4 + wv) * 64 + l]
             + accs_f[((3 * 3 + 0) * 4 + wv) * 64 + l];
    float s1 = accs_f[((0 * 3 + 1) * 4 + wv) * 64 + l]
             + accs_f[((1 * 3 + 1) * 4 + wv) * 64 + l]
             + accs_f[((2 * 3 + 1) * 4 + wv) * 64 + l]
             + accs_f[((3 * 3 + 1) * 4 + wv) * 64 + l];
    float s2 = accs_f[((0 * 3 + 2) * 4 + wv) * 64 + l]
             + accs_f[((1 * 3 + 2) * 4 + wv) * 64 + l]
             + accs_f[((2 * 3 + 2) * 4 + wv) * 64 + l]
             + accs_f[((3 * 3 + 2) * 4 + wv) * 64 + l];
    const float* gp = gi_s + (size_t)row * 1536 + col;
    const float hv = h_load32(hold + (size_t)row * 512 + col);
    const float r = sigmoidf_(gp[0]    + s0 + bhh[col]);
    const float z = sigmoidf_(gp[512]  + s1 + bhh[512 + col]);
    const float n = tanhf(gp[1024] + r * (s2 + bhh[1024 + col]));
    h_store32(hnew + (size_t)row * 512 + col, (1.0f - z) * n + z * hv);
    __syncthreads();
}

__global__ __launch_bounds__(256, 2) void gru_step_fb(
    const float* __restrict__ gi_s,
    const unsigned short* __restrict__ whhH,
    const unsigned short* __restrict__ whhL,
    const float* __restrict__ bhh,
    const float* __restrict__ hold, float* __restrict__ hnew)
{
    __shared__ float accs_f[4 * 3 * 4 * 64];
    gru_tile_body(accs_f, gi_s, whhH, whhL, bhh, hold, hnew,
                  threadIdx.x, blockIdx.x >> 5, blockIdx.x & 31);
}

// ---- Phase 3 fp32 GEMM (exact; known-good) ----
template<bool TANH>
__global__ __launch_bounds__(256) void gemm_nt_bias(
    const float* __restrict__ A, const float* __restrict__ B,
    const float* __restrict__ bias, float* __restrict__ C,
    const int N, const int K)
{
    __shared__ float As[32][68];
    __shared__ float Bs[32][68];
    const int nb = blockIdx.x, mb = blockIdx.y;
    const int t  = threadIdx.x;
    const int tx = t & 15, ty = t >> 4;
    const int lr = t >> 3;
    const int lk = (t & 7) << 2;
    const float* pA = A + (size_t)(mb * 64 + lr) * K + lk;
    const float* pB = B + (size_t)(nb * 64 + lr) * K + lk;
    float acc[4][4];
#pragma unroll
    for (int i = 0; i < 4; ++i)
#pragma unroll
        for (int j = 0; j < 4; ++j) acc[i][j] = 0.0f;
    for (int kk = 0; kk < K; kk += 32) {
        const float4 a0 = *(const float4*)(pA + kk);
        const float4 a1 = *(const float4*)(pA + (size_t)32 * K + kk);
        const float4 b0 = *(const float4*)(pB + kk);
        const float4 b1 = *(const float4*)(pB + (size_t)32 * K + kk);
        __syncthreads();
        As[lk+0][lr] = a0.x; As[lk+1][lr] = a0.y; As[lk+2][lr] = a0.z; As[lk+3][lr] = a0.w;
        As[lk+0][lr+32] = a1.x; As[lk+1][lr+32] = a1.y; As[lk+2][lr+32] = a1.z; As[lk+3][lr+32] = a1.w;
        Bs[lk+0][lr] = b0.x; Bs[lk+1][lr] = b0.y; Bs[lk+2][lr] = b0.z; Bs[lk+3][lr] = b0.w;
        Bs[lk+0][lr+32] = b1.x; Bs[lk+1][lr+32] = b1.y; Bs[lk+2][lr+32] = b1.z; Bs[lk+3][lr+32] = b1.w;
        __syncthreads();
#pragma unroll
        for (int k = 0; k < 32; ++k) {
            const float4 av = *(const float4*)&As[k][ty << 2];
            const float4 bv = *(const float4*)&Bs[k][tx << 2];
            acc[0][0] += av.x * bv.x; acc[0][1] += av.x * bv.y; acc[0][2] += av.x * bv.z; acc[0][3] += av.x * bv.w;
            acc[1][0] += av.y * bv.x; acc[1][1] += av.y * bv.y; acc[1][2] += av.y * bv.z; acc[1][3] += av.y * bv.w;
            acc[2][0] += av.z * bv.x; acc[2][1] += av.z * bv.y; acc[2][2] += av.z * bv.z; acc[2][3] += av.z * bv.w;
            acc[3][0] += av.w * bv.x; acc[3][1] += av.w * bv.y; acc[3][2] += av.w * bv.z; acc[3][3] += av.w * bv.w;
        }
    }
    const int crow = mb * 64 + (ty << 2);
    const int ccol = nb * 64 + (tx << 2);
    const float4 bv = *(const float4*)(bias + ccol);
#pragma unroll
    for (int i = 0; i < 4; ++i) {
        float4 o;
        o.x = acc[i][0] + bv.x; o.y = acc[i][1] + bv.y;
        o.z = acc[i][2] + bv.z; o.w = acc[i][3] + bv.w;
        if (TANH) { o.x = tanhf(o.x); o.y = tanhf(o.y); o.z = tanhf(o.z); o.w = tanhf(o.w); }
        *(float4*)(C + (size_t)(crow + i) * N + ccol) = o;
    }
}

__global__ __launch_bounds__(256) void value_head(
    const float* __restrict__ out1, const float* __restrict__ W2,
    const float* __restrict__ b2, float* __restrict__ out)
{
    const int b = blockIdx.x, t = threadIdx.x;
    float p = out1[(size_t)b * 512 + t] * W2[t]
            + out1[(size_t)b * 512 + 256 + t] * W2[256 + t];
#pragma unroll
    for (int off = 32; off > 0; off >>= 1) p += __shfl_down(p, off, 64);
    __shared__ float ps[4];
    if ((t & 63) == 0) ps[t >> 6] = p;
    __syncthreads();
    if (t == 0) out[b] = tanhf(ps[0] + ps[1] + ps[2] + ps[3] + b2[0]);
}

extern "C" void kernel_launch(void* const* d_in, const int* in_sizes, int n_in,
                              void* d_out, int out_size, void* d_ws, size_t ws_size,
                              hipStream_t stream)
{
    (void)in_sizes; (void)n_in; (void)out_size;
    const float* input = (const float*)d_in[0];   // [256,256,512]
    const float* w_ih  = (const float*)d_in[1];   // [1536,512]
    const float* w_hh  = (const float*)d_in[2];   // [1536,512]
    const float* b_ih  = (const float*)d_in[3];   // [1536]
    const float* b_hh  = (const float*)d_in[4];   // [1536]
    const float* W1    = (const float*)d_in[5];   // [512,512]
    const float* b1    = (const float*)d_in[6];   // [512]
    const float* W2    = (const float*)d_in[7];   // [512]
    const float* b2    = (const float*)d_in[8];   // [1]
    float* out = (float*)d_out;
    float* ws  = (float*)d_ws;

    // ws layout in FLOAT SLOTS. One [1536,512] bf16 buffer = 786432 ushorts
    // = 1,572,864 B = 393,216 float slots.
    float* hA = ws;                                        // [0, 131072)
    float* hB = ws + 131072;                               // [131072, 262144)
    float* o1 = ws + 262144;                               // [262144, 393216)
    unsigned short* wihH = (unsigned short*)(ws + 393216); // [393216, 786432)
    unsigned short* wihL = (unsigned short*)(ws + 786432); // [786432, 1179648)
    unsigned short* whhH = (unsigned short*)(ws + 1179648);// [1179648, 1572864)
    unsigned short* whhL = (unsigned short*)(ws + 1572864);// [1572864, 1966080)
    unsigned* flags = (unsigned*)(ws + 1966080);           // 512 u32
    float* gi = ws + 1966592;

    const size_t per_step = 256 * 1536;             // gi floats per timestep
    const size_t base = 1966592;
    const size_t avail = (ws_size / 4 > base) ? ws_size / 4 - base : 0;
    int Tc = (int)(avail / per_step);
    if (Tc > 256) Tc = 256;
    if (Tc < 1) Tc = 1;

    // Uniform state every launch/replay: h ping-pong AND flags zeroed.
    hipMemsetAsync(hA, 0, 262144 * sizeof(float), stream);    // hA + hB = 0
    hipMemsetAsync(flags, 0, 512 * sizeof(unsigned), stream); // barrier gen 0

    cast_split<<<768, 256, 0, stream>>>(w_ih, wihH, wihL, 196608);
    cast_split<<<768, 256, 0, stream>>>(w_hh, whhH, whhL, 196608);

    for (int t0 = 0; t0 < 256; t0 += Tc) {
        const int tc = (t0 + Tc <= 256) ? Tc : (256 - t0);
        const int Mc = tc * 256;
        // Phase 1 (chunk): gi = X_chunk @ w_ih^T + b_ih
        gemm_gi_mfma<<<dim3(12, Mc / 128), 256, 0, stream>>>(
            input + (size_t)t0 * 256 * 512, wihH, wihL, b_ih, gi);
        // Phase 2 (chunk): coop persistent kernel + per-group barrier.
        {
            const float* a_gi = gi;
            const unsigned short* a_wh = whhH; const unsigned short* a_wl = whhL;
            const float* a_bh = b_hh;
            float* a_hA = hA; float* a_hB = hB;
            unsigned* a_fl = flags;
            int a_t0 = t0; int a_tc = tc;
            void* args[] = {&a_gi, &a_wh, &a_wl, &a_bh, &a_hA, &a_hB, &a_fl, &a_t0, &a_tc};
            hipError_t rc = hipLaunchCooperativeKernel(
                (const void*)gru_coop, dim3(512), dim3(256), args, 0, stream);
            if (rc != hipSuccess) {
                // Fallback: per-step launches (kernel boundary = grid barrier)
                for (int s = 0; s < tc; ++s) {
                    const int t = t0 + s;
                    const float* hold = (t & 1) ? hB : hA;
                    float* hnew = (t & 1) ? hA : hB;
                    gru_step_fb<<<dim3(512), 256, 0, stream>>>(
                        gi + (size_t)s * per_step, whhH, whhL, b_hh, hold, hnew);
                }
            }
        }
    }

    // Phase 3: final h is in hA (after 256 steps, even count).
    gemm_nt_bias<true><<<dim3(512 / 64, 256 / 64), 256, 0, stream>>>(
        hA, W1, b1, o1, 512, 512);
    value_head<<<256, 256, 0, stream>>>(o1, W2, b2, out);
}

// Round 15
// 2054.520 us; speedup vs baseline: 1.7620x; 1.1934x over previous
//
#include <hip/hip_runtime.h>
#include <hip/hip_bf16.h>

typedef __attribute__((ext_vector_type(8))) short short8v;   // 8 bf16 = 16 B
typedef __attribute__((ext_vector_type(4))) float f32x4;

union SV { short8v v; unsigned short u[8]; };
union FU { float f; unsigned u; };
union QF { unsigned long long q[4]; float4 v[2]; };

// Truncation split: x ~= hi + lo, residual <= 2^-16 |x|.
__device__ __forceinline__ void split2(float x, unsigned short& hi, unsigned short& lo) {
    FU a; a.f = x;
    hi = (unsigned short)(a.u >> 16);
    FU h; h.u = a.u & 0xffff0000u;
    FU r; r.f = x - h.f;              // exact
    lo = (unsigned short)(r.u >> 16);
}
__device__ __forceinline__ void split8(const float4 a0, const float4 a1, SV& h, SV& l) {
    split2(a0.x, h.u[0], l.u[0]); split2(a0.y, h.u[1], l.u[1]);
    split2(a0.z, h.u[2], l.u[2]); split2(a0.w, h.u[3], l.u[3]);
    split2(a1.x, h.u[4], l.u[4]); split2(a1.y, h.u[5], l.u[5]);
    split2(a1.z, h.u[6], l.u[6]); split2(a1.w, h.u[7], l.u[7]);
}
__device__ __forceinline__ float sigmoidf_(float x) {
    return 1.0f / (1.0f + __expf(-x));
}

// Agent-scope (LLC-coherent, L2-bypassing) h accessors — all cross-step h
// traffic, so no cache-maintenance fences are needed anywhere.
__device__ __forceinline__ unsigned long long h_load64(const float* p) {
    return __hip_atomic_load((const unsigned long long*)p,
                             __ATOMIC_RELAXED, __HIP_MEMORY_SCOPE_AGENT);
}
__device__ __forceinline__ float h_load32(const float* p) {
    FU u; u.u = __hip_atomic_load((const unsigned*)p,
                                  __ATOMIC_RELAXED, __HIP_MEMORY_SCOPE_AGENT);
    return u.f;
}
__device__ __forceinline__ void h_store32(float* p, float v) {
    FU u; u.f = v;
    __hip_atomic_store((unsigned*)p, u.u,
                       __ATOMIC_RELAXED, __HIP_MEMORY_SCOPE_AGENT);
}

// Per-rt-group barrier — R9/R10/R12-proven protocol (arrive+poll adjacent,
// tightly fenced, no work inside). R15 change: ONE 128-B LLC LINE PER FLAG
// (stride 32 u32). R14's dense flags put a group's 32 arrive-stores on 2
// cache lines -> same-line stores from 32 CUs serialize at the LLC (~100ns
// per ownership transfer, the R7 lesson applied to plain stores). Padded,
// the 32 arrives are fully parallel; poll lanes each spin on their own line.
__device__ __forceinline__ void group_barrier(unsigned* gf, const int ct,
                                              const unsigned gen) {
    __builtin_amdgcn_s_waitcnt(0);
    __syncthreads();
    __atomic_signal_fence(__ATOMIC_SEQ_CST);
    if (threadIdx.x == 0)
        __hip_atomic_store(&gf[ct * 32], gen,
                           __ATOMIC_RELAXED, __HIP_MEMORY_SCOPE_AGENT);
    if (threadIdx.x < 32) {
        while (__hip_atomic_load(&gf[threadIdx.x * 32],
                                 __ATOMIC_RELAXED, __HIP_MEMORY_SCOPE_AGENT) < gen)
            __builtin_amdgcn_s_sleep(1);
    }
    __atomic_signal_fence(__ATOMIC_SEQ_CST);
    __syncthreads();
}

// ---- split-cast weights f32 -> (hi, lo) bf16, once ----
__global__ __launch_bounds__(256) void cast_split(
    const float* __restrict__ in, unsigned short* __restrict__ hi,
    unsigned short* __restrict__ lo, int n4)
{
    int i = blockIdx.x * 256 + threadIdx.x;
    if (i < n4) {
        float4 v = ((const float4*)in)[i];
        ushort4 h, l;
        split2(v.x, h.x, l.x); split2(v.y, h.y, l.y);
        split2(v.z, h.z, l.z); split2(v.w, h.w, l.w);
        ((ushort4*)hi)[i] = h;
        ((ushort4*)lo)[i] = l;
    }
}

// ---- Phase 1: gi = X @ w_ih^T + b_ih. Split-bf16 MFMA (3 products). ----
// 128x128 tile amortizes w_ih reads over 128 rows (the reason phase-split
// beats fusion: fused per-16-row blocks paid 8x this weight traffic).
__global__ __launch_bounds__(256, 2) void gemm_gi_mfma(
    const float* __restrict__ A,            // [M,512] fp32
    const unsigned short* __restrict__ Bh,  // [1536,512] bf16 hi
    const unsigned short* __restrict__ Bl,  // [1536,512] bf16 lo
    const float* __restrict__ bias,         // [1536]
    float* __restrict__ C)                  // [M,1536]
{
    __shared__ __attribute__((aligned(16))) unsigned char lds[65536];
    const int t = threadIdx.x;
    const int l = t & 63, w = t >> 6;
    const int nb = blockIdx.x, mb = blockIdx.y;
    const int p = t & 7;
    const int rbase = t >> 3;
    f32x4 acc[4][4] = {};

    for (int kk = 0; kk < 512; kk += 64) {
#pragma unroll
        for (int i = 0; i < 4; ++i) {
            const int r = i * 32 + rbase;
            const int q = p ^ (r & 7);
            const float* ga = A + (size_t)(mb * 128 + r) * 512 + kk + q * 8;
            SV ah, al;
            split8(*(const float4*)ga, *(const float4*)(ga + 4), ah, al);
            const int o = r * 128 + p * 16;
            *(short8v*)&lds[o] = ah.v;
            *(short8v*)&lds[16384 + o] = al.v;
            const size_t gb = (size_t)(nb * 128 + r) * 512 + kk + q * 8;
            *(short8v*)&lds[32768 + o] = *(const short8v*)(Bh + gb);
            *(short8v*)&lds[49152 + o] = *(const short8v*)(Bl + gb);
        }
        __syncthreads();
        const int mr0 = (w >> 1) * 64, nc0 = (w & 1) * 64;
#pragma unroll
        for (int kk2 = 0; kk2 < 2; ++kk2) {
            const int kap = kk2 * 4 + (l >> 4);
            short8v ah[4], al[4], bh[4], bl[4];
#pragma unroll
            for (int i = 0; i < 4; ++i) {
                const int row = mr0 + i * 16 + (l & 15);
                const int off = row * 128 + ((kap ^ (row & 7)) * 16);
                ah[i] = *(const short8v*)&lds[off];
                al[i] = *(const short8v*)&lds[16384 + off];
            }
#pragma unroll
            for (int j = 0; j < 4; ++j) {
                const int bn = nc0 + j * 16 + (l & 15);
                const int off = bn * 128 + ((kap ^ (bn & 7)) * 16);
                bh[j] = *(const short8v*)&lds[32768 + off];
                bl[j] = *(const short8v*)&lds[49152 + off];
            }
#pragma unroll
            for (int i = 0; i < 4; ++i)
#pragma unroll
                for (int j = 0; j < 4; ++j) {
                    acc[i][j] = __builtin_amdgcn_mfma_f32_16x16x32_bf16(ah[i], bh[j], acc[i][j], 0, 0, 0);
                    acc[i][j] = __builtin_amdgcn_mfma_f32_16x16x32_bf16(ah[i], bl[j], acc[i][j], 0, 0, 0);
                    acc[i][j] = __builtin_amdgcn_mfma_f32_16x16x32_bf16(al[i], bh[j], acc[i][j], 0, 0, 0);
                }
        }
        __syncthreads();
    }
    const int mr0 = (w >> 1) * 64, nc0 = (w & 1) * 64;
#pragma unroll
    for (int j = 0; j < 4; ++j) {
        const int col = nb * 128 + nc0 + j * 16 + (l & 15);
        const float bv = bias[col];
#pragma unroll
        for (int i = 0; i < 4; ++i) {
            const int row0 = mb * 128 + mr0 + i * 16 + (l >> 4) * 4;
#pragma unroll
            for (int rg = 0; rg < 4; ++rg)
                C[(size_t)(row0 + rg) * 1536 + col] = acc[i][j][rg] + bv;
        }
    }
}

// ---- Phase 2: recur-only persistent kernel (R14 body, padded flags). ----
__global__ __launch_bounds__(256, 2) void gru_coop(
    const float* __restrict__ gi,              // [tc,256,1536] chunk base
    const unsigned short* __restrict__ whhH,
    const unsigned short* __restrict__ whhL,
    const float* __restrict__ bhh,
    float* __restrict__ hA, float* __restrict__ hB,
    unsigned* __restrict__ flags,              // 16 groups x 32 flags x 32 u32
    const int t0, const int tc)
{
    __shared__ float accs_f[4 * 3 * 4 * 64];   // 12 KB
    const int tid = threadIdx.x;
    const int l = tid & 63, wv = tid >> 6;
    const int ct = blockIdx.x & 31;
    const int rt = blockIdx.x >> 5;
    const int arow = l & 15, ksl = l >> 4, kbase = wv * 128;
    const int c0 = ct * 16, row0 = rt * 16;
    unsigned* gf = flags + rt * 1024;
    const int col = c0 + arow;
    const int row = row0 + (ksl << 2) + wv;
    const float bhr = bhh[col], bhz = bhh[512 + col], bhn = bhh[1024 + col];

    // Loop-invariant w_hh fragments (compiler re-sinks under VGPR cap —
    // still saves per-step addressing; keep).
    short8v wbh[4][3], wbl[4][3];
#pragma unroll
    for (int j = 0; j < 4; ++j) {
        const int ko = kbase + j * 32 + ksl * 8;
#pragma unroll
        for (int g = 0; g < 3; ++g) {
            const size_t wo = (size_t)((g << 9) + c0 + arow) * 512 + ko;
            wbh[j][g] = *(const short8v*)(whhH + wo);
            wbl[j][g] = *(const short8v*)(whhL + wo);
        }
    }

    for (int s = 0; s < tc; ++s) {
        const int t = t0 + s;
        const float* hold = (t & 1) ? hB : hA;
        float* hnew = (t & 1) ? hA : hB;
        const float* gi_s = gi + (size_t)s * (256 * 1536);

        // h loads (LLC atomics) + hv, issued together.
        unsigned long long a_raw[4][4];
        const float* ha = hold + (size_t)(row0 + arow) * 512 + kbase + ksl * 8;
#pragma unroll
        for (int j = 0; j < 4; ++j)
#pragma unroll
            for (int q = 0; q < 4; ++q)
                a_raw[j][q] = h_load64(ha + j * 32 + q * 2);
        const float hv = h_load32(hold + (size_t)row * 512 + col);

        // recur MFMAs.
        f32x4 acc[3] = {};
#pragma unroll
        for (int j = 0; j < 4; ++j) {
            QF buf;
#pragma unroll
            for (int q = 0; q < 4; ++q) buf.q[q] = a_raw[j][q];
            SV ah, al;
            split8(buf.v[0], buf.v[1], ah, al);
#pragma unroll
            for (int g = 0; g < 3; ++g) {
                acc[g] = __builtin_amdgcn_mfma_f32_16x16x32_bf16(ah.v, wbh[j][g], acc[g], 0, 0, 0);
                acc[g] = __builtin_amdgcn_mfma_f32_16x16x32_bf16(ah.v, wbl[j][g], acc[g], 0, 0, 0);
                acc[g] = __builtin_amdgcn_mfma_f32_16x16x32_bf16(al.v, wbh[j][g], acc[g], 0, 0, 0);
            }
        }

        // Exchange partials across the 4 K-quarter waves.
#pragma unroll
        for (int g = 0; g < 3; ++g)
#pragma unroll
            for (int rg = 0; rg < 4; ++rg)
                accs_f[((wv * 3 + g) * 4 + rg) * 64 + l] = acc[g][rg];
        __syncthreads();

        const float s0 = accs_f[((0 * 3 + 0) * 4 + wv) * 64 + l]
                       + accs_f[((1 * 3 + 0) * 4 + wv) * 64 + l]
                       + accs_f[((2 * 3 + 0) * 4 + wv) * 64 + l]
                       + accs_f[((3 * 3 + 0) * 4 + wv) * 64 + l];
        const float s1 = accs_f[((0 * 3 + 1) * 4 + wv) * 64 + l]
                       + accs_f[((1 * 3 + 1) * 4 + wv) * 64 + l]
                       + accs_f[((2 * 3 + 1) * 4 + wv) * 64 + l]
                       + accs_f[((3 * 3 + 1) * 4 + wv) * 64 + l];
        const float s2 = accs_f[((0 * 3 + 2) * 4 + wv) * 64 + l]
                       + accs_f[((1 * 3 + 2) * 4 + wv) * 64 + l]
                       + accs_f[((2 * 3 + 2) * 4 + wv) * 64 + l]
                       + accs_f[((3 * 3 + 2) * 4 + wv) * 64 + l];
        const float* gp = gi_s + (size_t)row * 1536 + col;
        const float r = sigmoidf_(gp[0]    + s0 + bhr);
        const float z = sigmoidf_(gp[512]  + s1 + bhz);
        const float n = tanhf(gp[1024] + r * (s2 + bhn));
        h_store32(hnew + (size_t)row * 512 + col, (1.0f - z) * n + z * hv);

        if (s + 1 < tc)
            group_barrier(gf, ct, (unsigned)(t + 1));  // also covers LDS WAR
        else
            __syncthreads();                           // chunk-final WAR close
    }
}

// ---- Phase 2b tile body (fallback only; loads w per step) ----
__device__ __forceinline__ void gru_tile_body(
    float* accs_f,
    const float* __restrict__ gi_s,
    const unsigned short* __restrict__ whhH,
    const unsigned short* __restrict__ whhL,
    const float* __restrict__ bhh,
    const float* __restrict__ hold,
    float* __restrict__ hnew,
    const int tid, const int rt, const int ct)
{
    const int l = tid & 63, wv = tid >> 6;
    const int c0 = ct * 16, row0 = rt * 16;
    const int arow = l & 15;
    const int ksl  = l >> 4;
    const int kbase = wv * 128;

    unsigned long long a_raw[4][4];
    const float* ha = hold + (size_t)(row0 + arow) * 512 + kbase + ksl * 8;
#pragma unroll
    for (int j = 0; j < 4; ++j)
#pragma unroll
        for (int q = 0; q < 4; ++q)
            a_raw[j][q] = h_load64(ha + j * 32 + q * 2);

    f32x4 acc[3] = {};
#pragma unroll
    for (int j = 0; j < 4; ++j) {
        QF buf;
#pragma unroll
        for (int q = 0; q < 4; ++q) buf.q[q] = a_raw[j][q];
        SV ah, al;
        split8(buf.v[0], buf.v[1], ah, al);
        const int ko = kbase + j * 32 + ksl * 8;
#pragma unroll
        for (int g = 0; g < 3; ++g) {
            const size_t wo = (size_t)((g << 9) + c0 + arow) * 512 + ko;
            const short8v bh = *(const short8v*)(whhH + wo);
            const short8v bl = *(const short8v*)(whhL + wo);
            acc[g] = __builtin_amdgcn_mfma_f32_16x16x32_bf16(ah.v, bh, acc[g], 0, 0, 0);
            acc[g] = __builtin_amdgcn_mfma_f32_16x16x32_bf16(ah.v, bl, acc[g], 0, 0, 0);
            acc[g] = __builtin_amdgcn_mfma_f32_16x16x32_bf16(al.v, bh, acc[g], 0, 0, 0);
        }
    }
#pragma unroll
    for (int g = 0; g < 3; ++g)
#pragma unroll
        for (int rg = 0; rg < 4; ++rg)
            accs_f[((wv * 3 + g) * 4 + rg) * 64 + l] = acc[g][rg];
    __syncthreads();

    const int col = c0 + arow;
    const int row = row0 + (ksl << 2) + wv;
    float s0 = accs_f[((0 * 3 + 0) * 4 + wv) * 64 + l]
             + accs_f[((1 * 3 + 0) * 4 + wv) * 64 + l]
             + accs_f[((2 * 3 + 0) * 4 + wv) * 64 + l]
             + accs_f[((3 * 3 + 0) * 4 + wv) * 64 + l];
    float s1 = accs_f[((0 * 3 + 1) * 4 + wv) * 64 + l]
             + accs_f[((1 * 3 + 1) * 4 + wv) * 64 + l]
             + accs_f[((2 * 3 + 1) * 4 + wv) * 64 + l]
             + accs_f[((3 * 3 + 1) * 4 + wv) * 64 + l];
    float s2 = accs_f[((0 * 3 + 2) * 4 + wv) * 64 + l]
             + accs_f[((1 * 3 + 2) * 4 + wv) * 64 + l]
             + accs_f[((2 * 3 + 2) * 4 + wv) * 64 + l]
             + accs_f[((3 * 3 + 2) * 4 + wv) * 64 + l];
    const float* gp = gi_s + (size_t)row * 1536 + col;
    const float hv = h_load32(hold + (size_t)row * 512 + col);
    const float r = sigmoidf_(gp[0]    + s0 + bhh[col]);
    const float z = sigmoidf_(gp[512]  + s1 + bhh[512 + col]);
    const float n = tanhf(gp[1024] + r * (s2 + bhh[1024 + col]));
    h_store32(hnew + (size_t)row * 512 + col, (1.0f - z) * n + z * hv);
    __syncthreads();
}

__global__ __launch_bounds__(256, 2) void gru_step_fb(
    const float* __restrict__ gi_s,
    const unsigned short* __restrict__ whhH,
    const unsigned short* __restrict__ whhL,
    const float* __restrict__ bhh,
    const float* __restrict__ hold, float* __restrict__ hnew)
{
    __shared__ float accs_f[4 * 3 * 4 * 64];
    gru_tile_body(accs_f, gi_s, whhH, whhL, bhh, hold, hnew,
                  threadIdx.x, blockIdx.x >> 5, blockIdx.x & 31);
}

// ---- Phase 3 fp32 GEMM (exact; known-good) ----
template<bool TANH>
__global__ __launch_bounds__(256) void gemm_nt_bias(
    const float* __restrict__ A, const float* __restrict__ B,
    const float* __restrict__ bias, float* __restrict__ C,
    const int N, const int K)
{
    __shared__ float As[32][68];
    __shared__ float Bs[32][68];
    const int nb = blockIdx.x, mb = blockIdx.y;
    const int t  = threadIdx.x;
    const int tx = t & 15, ty = t >> 4;
    const int lr = t >> 3;
    const int lk = (t & 7) << 2;
    const float* pA = A + (size_t)(mb * 64 + lr) * K + lk;
    const float* pB = B + (size_t)(nb * 64 + lr) * K + lk;
    float acc[4][4];
#pragma unroll
    for (int i = 0; i < 4; ++i)
#pragma unroll
        for (int j = 0; j < 4; ++j) acc[i][j] = 0.0f;
    for (int kk = 0; kk < K; kk += 32) {
        const float4 a0 = *(const float4*)(pA + kk);
        const float4 a1 = *(const float4*)(pA + (size_t)32 * K + kk);
        const float4 b0 = *(const float4*)(pB + kk);
        const float4 b1 = *(const float4*)(pB + (size_t)32 * K + kk);
        __syncthreads();
        As[lk+0][lr] = a0.x; As[lk+1][lr] = a0.y; As[lk+2][lr] = a0.z; As[lk+3][lr] = a0.w;
        As[lk+0][lr+32] = a1.x; As[lk+1][lr+32] = a1.y; As[lk+2][lr+32] = a1.z; As[lk+3][lr+32] = a1.w;
        Bs[lk+0][lr] = b0.x; Bs[lk+1][lr] = b0.y; Bs[lk+2][lr] = b0.z; Bs[lk+3][lr] = b0.w;
        Bs[lk+0][lr+32] = b1.x; Bs[lk+1][lr+32] = b1.y; Bs[lk+2][lr+32] = b1.z; Bs[lk+3][lr+32] = b1.w;
        __syncthreads();
#pragma unroll
        for (int k = 0; k < 32; ++k) {
            const float4 av = *(const float4*)&As[k][ty << 2];
            const float4 bv = *(const float4*)&Bs[k][tx << 2];
            acc[0][0] += av.x * bv.x; acc[0][1] += av.x * bv.y; acc[0][2] += av.x * bv.z; acc[0][3] += av.x * bv.w;
            acc[1][0] += av.y * bv.x; acc[1][1] += av.y * bv.y; acc[1][2] += av.y * bv.z; acc[1][3] += av.y * bv.w;
            acc[2][0] += av.z * bv.x; acc[2][1] += av.z * bv.y; acc[2][2] += av.z * bv.z; acc[2][3] += av.z * bv.w;
            acc[3][0] += av.w * bv.x; acc[3][1] += av.w * bv.y; acc[3][2] += av.w * bv.z; acc[3][3] += av.w * bv.w;
        }
    }
    const int crow = mb * 64 + (ty << 2);
    const int ccol = nb * 64 + (tx << 2);
    const float4 bv = *(const float4*)(bias + ccol);
#pragma unroll
    for (int i = 0; i < 4; ++i) {
        float4 o;
        o.x = acc[i][0] + bv.x; o.y = acc[i][1] + bv.y;
        o.z = acc[i][2] + bv.z; o.w = acc[i][3] + bv.w;
        if (TANH) { o.x = tanhf(o.x); o.y = tanhf(o.y); o.z = tanhf(o.z); o.w = tanhf(o.w); }
        *(float4*)(C + (size_t)(crow + i) * N + ccol) = o;
    }
}

__global__ __launch_bounds__(256) void value_head(
    const float* __restrict__ out1, const float* __restrict__ W2,
    const float* __restrict__ b2, float* __restrict__ out)
{
    const int b = blockIdx.x, t = threadIdx.x;
    float p = out1[(size_t)b * 512 + t] * W2[t]
            + out1[(size_t)b * 512 + 256 + t] * W2[256 + t];
#pragma unroll
    for (int off = 32; off > 0; off >>= 1) p += __shfl_down(p, off, 64);
    __shared__ float ps[4];
    if ((t & 63) == 0) ps[t >> 6] = p;
    __syncthreads();
    if (t == 0) out[b] = tanhf(ps[0] + ps[1] + ps[2] + ps[3] + b2[0]);
}

extern "C" void kernel_launch(void* const* d_in, const int* in_sizes, int n_in,
                              void* d_out, int out_size, void* d_ws, size_t ws_size,
                              hipStream_t stream)
{
    (void)in_sizes; (void)n_in; (void)out_size;
    const float* input = (const float*)d_in[0];   // [256,256,512]
    const float* w_ih  = (const float*)d_in[1];   // [1536,512]
    const float* w_hh  = (const float*)d_in[2];   // [1536,512]
    const float* b_ih  = (const float*)d_in[3];   // [1536]
    const float* b_hh  = (const float*)d_in[4];   // [1536]
    const float* W1    = (const float*)d_in[5];   // [512,512]
    const float* b1    = (const float*)d_in[6];   // [512]
    const float* W2    = (const float*)d_in[7];   // [512]
    const float* b2    = (const float*)d_in[8];   // [1]
    float* out = (float*)d_out;
    float* ws  = (float*)d_ws;

    // ws layout in FLOAT SLOTS. One [1536,512] bf16 buffer = 786432 ushorts
    // = 1,572,864 B = 393,216 float slots.
    float* hA = ws;                                        // [0, 131072)
    float* hB = ws + 131072;                               // [131072, 262144)
    float* o1 = ws + 262144;                               // [262144, 393216)
    unsigned short* wihH = (unsigned short*)(ws + 393216); // [393216, 786432)
    unsigned short* wihL = (unsigned short*)(ws + 786432); // [786432, 1179648)
    unsigned short* whhH = (unsigned short*)(ws + 1179648);// [1179648, 1572864)
    unsigned short* whhL = (unsigned short*)(ws + 1572864);// [1572864, 1966080)
    unsigned* flags = (unsigned*)(ws + 1966080);           // 16*32*32 u32 = 16384 slots
    float* gi = ws + 1982464;

    const size_t per_step = 256 * 1536;             // gi floats per timestep
    const size_t base = 1982464;
    const size_t avail = (ws_size / 4 > base) ? ws_size / 4 - base : 0;
    int Tc = (int)(avail / per_step);
    if (Tc > 256) Tc = 256;
    if (Tc < 1) Tc = 1;

    // Uniform state every launch/replay: h ping-pong AND flags zeroed.
    hipMemsetAsync(hA, 0, 262144 * sizeof(float), stream);      // hA + hB = 0
    hipMemsetAsync(flags, 0, 16384 * sizeof(unsigned), stream); // barrier gen 0

    cast_split<<<768, 256, 0, stream>>>(w_ih, wihH, wihL, 196608);
    cast_split<<<768, 256, 0, stream>>>(w_hh, whhH, whhL, 196608);

    for (int t0 = 0; t0 < 256; t0 += Tc) {
        const int tc = (t0 + Tc <= 256) ? Tc : (256 - t0);
        const int Mc = tc * 256;
        // Phase 1 (chunk): gi = X_chunk @ w_ih^T + b_ih
        gemm_gi_mfma<<<dim3(12, Mc / 128), 256, 0, stream>>>(
            input + (size_t)t0 * 256 * 512, wihH, wihL, b_ih, gi);
        // Phase 2 (chunk): coop persistent kernel + per-group barrier.
        {
            const float* a_gi = gi;
            const unsigned short* a_wh = whhH; const unsigned short* a_wl = whhL;
            const float* a_bh = b_hh;
            float* a_hA = hA; float* a_hB = hB;
            unsigned* a_fl = flags;
            int a_t0 = t0; int a_tc = tc;
            void* args[] = {&a_gi, &a_wh, &a_wl, &a_bh, &a_hA, &a_hB, &a_fl, &a_t0, &a_tc};
            hipError_t rc = hipLaunchCooperativeKernel(
                (const void*)gru_coop, dim3(512), dim3(256), args, 0, stream);
            if (rc != hipSuccess) {
                // Fallback: per-step launches (kernel boundary = grid barrier)
                for (int s = 0; s < tc; ++s) {
                    const int t = t0 + s;
                    const float* hold = (t & 1) ? hB : hA;
                    float* hnew = (t & 1) ? hA : hB;
                    gru_step_fb<<<dim3(512), 256, 0, stream>>>(
                        gi + (size_t)s * per_step, whhH, whhL, b_hh, hold, hnew);
                }
            }
        }
    }

    // Phase 3: final h is in hA (after 256 steps, even count).
    gemm_nt_bias<true><<<dim3(512 / 64, 256 / 64), 256, 0, stream>>>(
        hA, W1, b1, o1, 512, 512);
    value_head<<<256, 256, 0, stream>>>(o1, W2, b2, out);
}

// Round 16
// 1981.634 us; speedup vs baseline: 1.8269x; 1.0368x over previous
//
#include <hip/hip_runtime.h>
#include <hip/hip_bf16.h>

typedef __attribute__((ext_vector_type(8))) short short8v;   // 8 bf16 = 16 B
typedef __attribute__((ext_vector_type(4))) float f32x4;

union SV { short8v v; unsigned short u[8]; };
union FU { float f; unsigned u; };
union QF { unsigned long long q[4]; float4 v[2]; };

// Truncation split: x ~= hi + lo, residual <= 2^-16 |x|.
__device__ __forceinline__ void split2(float x, unsigned short& hi, unsigned short& lo) {
    FU a; a.f = x;
    hi = (unsigned short)(a.u >> 16);
    FU h; h.u = a.u & 0xffff0000u;
    FU r; r.f = x - h.f;              // exact
    lo = (unsigned short)(r.u >> 16);
}
__device__ __forceinline__ void split8(const float4 a0, const float4 a1, SV& h, SV& l) {
    split2(a0.x, h.u[0], l.u[0]); split2(a0.y, h.u[1], l.u[1]);
    split2(a0.z, h.u[2], l.u[2]); split2(a0.w, h.u[3], l.u[3]);
    split2(a1.x, h.u[4], l.u[4]); split2(a1.y, h.u[5], l.u[5]);
    split2(a1.z, h.u[6], l.u[6]); split2(a1.w, h.u[7], l.u[7]);
}
__device__ __forceinline__ float sigmoidf_(float x) {
    return 1.0f / (1.0f + __expf(-x));
}

// Agent-scope (LLC-coherent, L2-bypassing) h accessors — all cross-step h
// traffic, so no cache-maintenance fences are needed anywhere.
__device__ __forceinline__ unsigned long long h_load64(const float* p) {
    return __hip_atomic_load((const unsigned long long*)p,
                             __ATOMIC_RELAXED, __HIP_MEMORY_SCOPE_AGENT);
}
__device__ __forceinline__ float h_load32(const float* p) {
    FU u; u.u = __hip_atomic_load((const unsigned*)p,
                                  __ATOMIC_RELAXED, __HIP_MEMORY_SCOPE_AGENT);
    return u.f;
}
__device__ __forceinline__ void h_store32(float* p, float v) {
    FU u; u.f = v;
    __hip_atomic_store((unsigned*)p, u.u,
                       __ATOMIC_RELAXED, __HIP_MEMORY_SCOPE_AGENT);
}

// Per-rt-group barrier — R9/R10/R12-proven protocol; R15's one-LLC-line-per
// -flag padding (stride 32 u32). Arrive+poll adjacent, tightly fenced.
__device__ __forceinline__ void group_barrier(unsigned* gf, const int ct,
                                              const unsigned gen) {
    __builtin_amdgcn_s_waitcnt(0);
    __syncthreads();
    __atomic_signal_fence(__ATOMIC_SEQ_CST);
    if (threadIdx.x == 0)
        __hip_atomic_store(&gf[ct * 32], gen,
                           __ATOMIC_RELAXED, __HIP_MEMORY_SCOPE_AGENT);
    if (threadIdx.x < 32) {
        while (__hip_atomic_load(&gf[threadIdx.x * 32],
                                 __ATOMIC_RELAXED, __HIP_MEMORY_SCOPE_AGENT) < gen)
            __builtin_amdgcn_s_sleep(1);
    }
    __atomic_signal_fence(__ATOMIC_SEQ_CST);
    __syncthreads();
}

// ---- split-cast weights f32 -> (hi, lo) bf16, once ----
__global__ __launch_bounds__(256) void cast_split(
    const float* __restrict__ in, unsigned short* __restrict__ hi,
    unsigned short* __restrict__ lo, int n4)
{
    int i = blockIdx.x * 256 + threadIdx.x;
    if (i < n4) {
        float4 v = ((const float4*)in)[i];
        ushort4 h, l;
        split2(v.x, h.x, l.x); split2(v.y, h.y, l.y);
        split2(v.z, h.z, l.z); split2(v.w, h.w, l.w);
        ((ushort4*)hi)[i] = h;
        ((ushort4*)lo)[i] = l;
    }
}

// ---- Phase 1: gi = X @ w_ih^T + b_ih. Split-bf16 MFMA (3 products). ----
// 128x128 tile amortizes w_ih reads over 128 rows.
__global__ __launch_bounds__(256, 2) void gemm_gi_mfma(
    const float* __restrict__ A,            // [M,512] fp32
    const unsigned short* __restrict__ Bh,  // [1536,512] bf16 hi
    const unsigned short* __restrict__ Bl,  // [1536,512] bf16 lo
    const float* __restrict__ bias,         // [1536]
    float* __restrict__ C)                  // [M,1536]
{
    __shared__ __attribute__((aligned(16))) unsigned char lds[65536];
    const int t = threadIdx.x;
    const int l = t & 63, w = t >> 6;
    const int nb = blockIdx.x, mb = blockIdx.y;
    const int p = t & 7;
    const int rbase = t >> 3;
    f32x4 acc[4][4] = {};

    for (int kk = 0; kk < 512; kk += 64) {
#pragma unroll
        for (int i = 0; i < 4; ++i) {
            const int r = i * 32 + rbase;
            const int q = p ^ (r & 7);
            const float* ga = A + (size_t)(mb * 128 + r) * 512 + kk + q * 8;
            SV ah, al;
            split8(*(const float4*)ga, *(const float4*)(ga + 4), ah, al);
            const int o = r * 128 + p * 16;
            *(short8v*)&lds[o] = ah.v;
            *(short8v*)&lds[16384 + o] = al.v;
            const size_t gb = (size_t)(nb * 128 + r) * 512 + kk + q * 8;
            *(short8v*)&lds[32768 + o] = *(const short8v*)(Bh + gb);
            *(short8v*)&lds[49152 + o] = *(const short8v*)(Bl + gb);
        }
        __syncthreads();
        const int mr0 = (w >> 1) * 64, nc0 = (w & 1) * 64;
#pragma unroll
        for (int kk2 = 0; kk2 < 2; ++kk2) {
            const int kap = kk2 * 4 + (l >> 4);
            short8v ah[4], al[4], bh[4], bl[4];
#pragma unroll
            for (int i = 0; i < 4; ++i) {
                const int row = mr0 + i * 16 + (l & 15);
                const int off = row * 128 + ((kap ^ (row & 7)) * 16);
                ah[i] = *(const short8v*)&lds[off];
                al[i] = *(const short8v*)&lds[16384 + off];
            }
#pragma unroll
            for (int j = 0; j < 4; ++j) {
                const int bn = nc0 + j * 16 + (l & 15);
                const int off = bn * 128 + ((kap ^ (bn & 7)) * 16);
                bh[j] = *(const short8v*)&lds[32768 + off];
                bl[j] = *(const short8v*)&lds[49152 + off];
            }
#pragma unroll
            for (int i = 0; i < 4; ++i)
#pragma unroll
                for (int j = 0; j < 4; ++j) {
                    acc[i][j] = __builtin_amdgcn_mfma_f32_16x16x32_bf16(ah[i], bh[j], acc[i][j], 0, 0, 0);
                    acc[i][j] = __builtin_amdgcn_mfma_f32_16x16x32_bf16(ah[i], bl[j], acc[i][j], 0, 0, 0);
                    acc[i][j] = __builtin_amdgcn_mfma_f32_16x16x32_bf16(al[i], bh[j], acc[i][j], 0, 0, 0);
                }
        }
        __syncthreads();
    }
    const int mr0 = (w >> 1) * 64, nc0 = (w & 1) * 64;
#pragma unroll
    for (int j = 0; j < 4; ++j) {
        const int col = nb * 128 + nc0 + j * 16 + (l & 15);
        const float bv = bias[col];
#pragma unroll
        for (int i = 0; i < 4; ++i) {
            const int row0 = mb * 128 + mr0 + i * 16 + (l >> 4) * 4;
#pragma unroll
            for (int rg = 0; rg < 4; ++rg)
                C[(size_t)(row0 + rg) * 1536 + col] = acc[i][j][rg] + bv;
        }
    }
}

// ---- Phase 2: recur-only persistent kernel (R15 + gi-load hoist). ----
// gi loads for the CURRENT step issue at the top of the step beside the h
// loads — their L2 latency hides under the MFMA/exchange phase instead of
// sitting naked on the post-sync epilogue chain.
__global__ __launch_bounds__(256, 2) void gru_coop(
    const float* __restrict__ gi,              // [tc,256,1536] chunk base
    const unsigned short* __restrict__ whhH,
    const unsigned short* __restrict__ whhL,
    const float* __restrict__ bhh,
    float* __restrict__ hA, float* __restrict__ hB,
    unsigned* __restrict__ flags,              // 16 groups x 32 flags x 32 u32
    const int t0, const int tc)
{
    __shared__ float accs_f[4 * 3 * 4 * 64];   // 12 KB
    const int tid = threadIdx.x;
    const int l = tid & 63, wv = tid >> 6;
    const int ct = blockIdx.x & 31;
    const int rt = blockIdx.x >> 5;
    const int arow = l & 15, ksl = l >> 4, kbase = wv * 128;
    const int c0 = ct * 16, row0 = rt * 16;
    unsigned* gf = flags + rt * 1024;
    const int col = c0 + arow;
    const int row = row0 + (ksl << 2) + wv;
    const float bhr = bhh[col], bhz = bhh[512 + col], bhn = bhh[1024 + col];

    // Loop-invariant w_hh fragments (compiler schedules under VGPR cap).
    short8v wbh[4][3], wbl[4][3];
#pragma unroll
    for (int j = 0; j < 4; ++j) {
        const int ko = kbase + j * 32 + ksl * 8;
#pragma unroll
        for (int g = 0; g < 3; ++g) {
            const size_t wo = (size_t)((g << 9) + c0 + arow) * 512 + ko;
            wbh[j][g] = *(const short8v*)(whhH + wo);
            wbl[j][g] = *(const short8v*)(whhL + wo);
        }
    }

    for (int s = 0; s < tc; ++s) {
        const int t = t0 + s;
        const float* hold = (t & 1) ? hB : hA;
        float* hnew = (t & 1) ? hA : hB;
        const float* gi_s = gi + (size_t)s * (256 * 1536);

        // Hoisted loads: gi (L2) + h (LLC atomics) + hv, all issued up front
        // so their latency hides under the MFMA/exchange phase.
        const float* gp = gi_s + (size_t)row * 1536 + col;
        const float gpr = gp[0];
        const float gpz = gp[512];
        const float gpn = gp[1024];
        unsigned long long a_raw[4][4];
        const float* ha = hold + (size_t)(row0 + arow) * 512 + kbase + ksl * 8;
#pragma unroll
        for (int j = 0; j < 4; ++j)
#pragma unroll
            for (int q = 0; q < 4; ++q)
                a_raw[j][q] = h_load64(ha + j * 32 + q * 2);
        const float hv = h_load32(hold + (size_t)row * 512 + col);

        // recur MFMAs.
        f32x4 acc[3] = {};
#pragma unroll
        for (int j = 0; j < 4; ++j) {
            QF buf;
#pragma unroll
            for (int q = 0; q < 4; ++q) buf.q[q] = a_raw[j][q];
            SV ah, al;
            split8(buf.v[0], buf.v[1], ah, al);
#pragma unroll
            for (int g = 0; g < 3; ++g) {
                acc[g] = __builtin_amdgcn_mfma_f32_16x16x32_bf16(ah.v, wbh[j][g], acc[g], 0, 0, 0);
                acc[g] = __builtin_amdgcn_mfma_f32_16x16x32_bf16(ah.v, wbl[j][g], acc[g], 0, 0, 0);
                acc[g] = __builtin_amdgcn_mfma_f32_16x16x32_bf16(al.v, wbh[j][g], acc[g], 0, 0, 0);
            }
        }

        // Exchange partials across the 4 K-quarter waves.
#pragma unroll
        for (int g = 0; g < 3; ++g)
#pragma unroll
            for (int rg = 0; rg < 4; ++rg)
                accs_f[((wv * 3 + g) * 4 + rg) * 64 + l] = acc[g][rg];
        __syncthreads();

        const float s0 = accs_f[((0 * 3 + 0) * 4 + wv) * 64 + l]
                       + accs_f[((1 * 3 + 0) * 4 + wv) * 64 + l]
                       + accs_f[((2 * 3 + 0) * 4 + wv) * 64 + l]
                       + accs_f[((3 * 3 + 0) * 4 + wv) * 64 + l];
        const float s1 = accs_f[((0 * 3 + 1) * 4 + wv) * 64 + l]
                       + accs_f[((1 * 3 + 1) * 4 + wv) * 64 + l]
                       + accs_f[((2 * 3 + 1) * 4 + wv) * 64 + l]
                       + accs_f[((3 * 3 + 1) * 4 + wv) * 64 + l];
        const float s2 = accs_f[((0 * 3 + 2) * 4 + wv) * 64 + l]
                       + accs_f[((1 * 3 + 2) * 4 + wv) * 64 + l]
                       + accs_f[((2 * 3 + 2) * 4 + wv) * 64 + l]
                       + accs_f[((3 * 3 + 2) * 4 + wv) * 64 + l];
        const float r = sigmoidf_(gpr + s0 + bhr);
        const float z = sigmoidf_(gpz + s1 + bhz);
        const float n = tanhf(gpn + r * (s2 + bhn));
        h_store32(hnew + (size_t)row * 512 + col, (1.0f - z) * n + z * hv);

        if (s + 1 < tc)
            group_barrier(gf, ct, (unsigned)(t + 1));  // also covers LDS WAR
        else
            __syncthreads();                           // chunk-final WAR close
    }
}

// ---- Phase 2b tile body (fallback only; loads w per step) ----
__device__ __forceinline__ void gru_tile_body(
    float* accs_f,
    const float* __restrict__ gi_s,
    const unsigned short* __restrict__ whhH,
    const unsigned short* __restrict__ whhL,
    const float* __restrict__ bhh,
    const float* __restrict__ hold,
    float* __restrict__ hnew,
    const int tid, const int rt, const int ct)
{
    const int l = tid & 63, wv = tid >> 6;
    const int c0 = ct * 16, row0 = rt * 16;
    const int arow = l & 15;
    const int ksl  = l >> 4;
    const int kbase = wv * 128;

    unsigned long long a_raw[4][4];
    const float* ha = hold + (size_t)(row0 + arow) * 512 + kbase + ksl * 8;
#pragma unroll
    for (int j = 0; j < 4; ++j)
#pragma unroll
        for (int q = 0; q < 4; ++q)
            a_raw[j][q] = h_load64(ha + j * 32 + q * 2);

    f32x4 acc[3] = {};
#pragma unroll
    for (int j = 0; j < 4; ++j) {
        QF buf;
#pragma unroll
        for (int q = 0; q < 4; ++q) buf.q[q] = a_raw[j][q];
        SV ah, al;
        split8(buf.v[0], buf.v[1], ah, al);
        const int ko = kbase + j * 32 + ksl * 8;
#pragma unroll
        for (int g = 0; g < 3; ++g) {
            const size_t wo = (size_t)((g << 9) + c0 + arow) * 512 + ko;
            const short8v bh = *(const short8v*)(whhH + wo);
            const short8v bl = *(const short8v*)(whhL + wo);
            acc[g] = __builtin_amdgcn_mfma_f32_16x16x32_bf16(ah.v, bh, acc[g], 0, 0, 0);
            acc[g] = __builtin_amdgcn_mfma_f32_16x16x32_bf16(ah.v, bl, acc[g], 0, 0, 0);
            acc[g] = __builtin_amdgcn_mfma_f32_16x16x32_bf16(al.v, bh, acc[g], 0, 0, 0);
        }
    }
#pragma unroll
    for (int g = 0; g < 3; ++g)
#pragma unroll
        for (int rg = 0; rg < 4; ++rg)
            accs_f[((wv * 3 + g) * 4 + rg) * 64 + l] = acc[g][rg];
    __syncthreads();

    const int col = c0 + arow;
    const int row = row0 + (ksl << 2) + wv;
    float s0 = accs_f[((0 * 3 + 0) * 4 + wv) * 64 + l]
             + accs_f[((1 * 3 + 0) * 4 + wv) * 64 + l]
             + accs_f[((2 * 3 + 0) * 4 + wv) * 64 + l]
             + accs_f[((3 * 3 + 0) * 4 + wv) * 64 + l];
    float s1 = accs_f[((0 * 3 + 1) * 4 + wv) * 64 + l]
             + accs_f[((1 * 3 + 1) * 4 + wv) * 64 + l]
             + accs_f[((2 * 3 + 1) * 4 + wv) * 64 + l]
             + accs_f[((3 * 3 + 1) * 4 + wv) * 64 + l];
    float s2 = accs_f[((0 * 3 + 2) * 4 + wv) * 64 + l]
             + accs_f[((1 * 3 + 2) * 4 + wv) * 64 + l]
             + accs_f[((2 * 3 + 2) * 4 + wv) * 64 + l]
             + accs_f[((3 * 3 + 2) * 4 + wv) * 64 + l];
    const float* gp = gi_s + (size_t)row * 1536 + col;
    const float hv = h_load32(hold + (size_t)row * 512 + col);
    const float r = sigmoidf_(gp[0]    + s0 + bhh[col]);
    const float z = sigmoidf_(gp[512]  + s1 + bhh[512 + col]);
    const float n = tanhf(gp[1024] + r * (s2 + bhh[1024 + col]));
    h_store32(hnew + (size_t)row * 512 + col, (1.0f - z) * n + z * hv);
    __syncthreads();
}

__global__ __launch_bounds__(256, 2) void gru_step_fb(
    const float* __restrict__ gi_s,
    const unsigned short* __restrict__ whhH,
    const unsigned short* __restrict__ whhL,
    const float* __restrict__ bhh,
    const float* __restrict__ hold, float* __restrict__ hnew)
{
    __shared__ float accs_f[4 * 3 * 4 * 64];
    gru_tile_body(accs_f, gi_s, whhH, whhL, bhh, hold, hnew,
                  threadIdx.x, blockIdx.x >> 5, blockIdx.x & 31);
}

// ---- Phase 3 fp32 GEMM (exact; known-good) ----
template<bool TANH>
__global__ __launch_bounds__(256) void gemm_nt_bias(
    const float* __restrict__ A, const float* __restrict__ B,
    const float* __restrict__ bias, float* __restrict__ C,
    const int N, const int K)
{
    __shared__ float As[32][68];
    __shared__ float Bs[32][68];
    const int nb = blockIdx.x, mb = blockIdx.y;
    const int t  = threadIdx.x;
    const int tx = t & 15, ty = t >> 4;
    const int lr = t >> 3;
    const int lk = (t & 7) << 2;
    const float* pA = A + (size_t)(mb * 64 + lr) * K + lk;
    const float* pB = B + (size_t)(nb * 64 + lr) * K + lk;
    float acc[4][4];
#pragma unroll
    for (int i = 0; i < 4; ++i)
#pragma unroll
        for (int j = 0; j < 4; ++j) acc[i][j] = 0.0f;
    for (int kk = 0; kk < K; kk += 32) {
        const float4 a0 = *(const float4*)(pA + kk);
        const float4 a1 = *(const float4*)(pA + (size_t)32 * K + kk);
        const float4 b0 = *(const float4*)(pB + kk);
        const float4 b1 = *(const float4*)(pB + (size_t)32 * K + kk);
        __syncthreads();
        As[lk+0][lr] = a0.x; As[lk+1][lr] = a0.y; As[lk+2][lr] = a0.z; As[lk+3][lr] = a0.w;
        As[lk+0][lr+32] = a1.x; As[lk+1][lr+32] = a1.y; As[lk+2][lr+32] = a1.z; As[lk+3][lr+32] = a1.w;
        Bs[lk+0][lr] = b0.x; Bs[lk+1][lr] = b0.y; Bs[lk+2][lr] = b0.z; Bs[lk+3][lr] = b0.w;
        Bs[lk+0][lr+32] = b1.x; Bs[lk+1][lr+32] = b1.y; Bs[lk+2][lr+32] = b1.z; Bs[lk+3][lr+32] = b1.w;
        __syncthreads();
#pragma unroll
        for (int k = 0; k < 32; ++k) {
            const float4 av = *(const float4*)&As[k][ty << 2];
            const float4 bv = *(const float4*)&Bs[k][tx << 2];
            acc[0][0] += av.x * bv.x; acc[0][1] += av.x * bv.y; acc[0][2] += av.x * bv.z; acc[0][3] += av.x * bv.w;
            acc[1][0] += av.y * bv.x; acc[1][1] += av.y * bv.y; acc[1][2] += av.y * bv.z; acc[1][3] += av.y * bv.w;
            acc[2][0] += av.z * bv.x; acc[2][1] += av.z * bv.y; acc[2][2] += av.z * bv.z; acc[2][3] += av.z * bv.w;
            acc[3][0] += av.w * bv.x; acc[3][1] += av.w * bv.y; acc[3][2] += av.w * bv.z; acc[3][3] += av.w * bv.w;
        }
    }
    const int crow = mb * 64 + (ty << 2);
    const int ccol = nb * 64 + (tx << 2);
    const float4 bv = *(const float4*)(bias + ccol);
#pragma unroll
    for (int i = 0; i < 4; ++i) {
        float4 o;
        o.x = acc[i][0] + bv.x; o.y = acc[i][1] + bv.y;
        o.z = acc[i][2] + bv.z; o.w = acc[i][3] + bv.w;
        if (TANH) { o.x = tanhf(o.x); o.y = tanhf(o.y); o.z = tanhf(o.z); o.w = tanhf(o.w); }
        *(float4*)(C + (size_t)(crow + i) * N + ccol) = o;
    }
}

__global__ __launch_bounds__(256) void value_head(
    const float* __restrict__ out1, const float* __restrict__ W2,
    const float* __restrict__ b2, float* __restrict__ out)
{
    const int b = blockIdx.x, t = threadIdx.x;
    float p = out1[(size_t)b * 512 + t] * W2[t]
            + out1[(size_t)b * 512 + 256 + t] * W2[256 + t];
#pragma unroll
    for (int off = 32; off > 0; off >>= 1) p += __shfl_down(p, off, 64);
    __shared__ float ps[4];
    if ((t & 63) == 0) ps[t >> 6] = p;
    __syncthreads();
    if (t == 0) out[b] = tanhf(ps[0] + ps[1] + ps[2] + ps[3] + b2[0]);
}

extern "C" void kernel_launch(void* const* d_in, const int* in_sizes, int n_in,
                              void* d_out, int out_size, void* d_ws, size_t ws_size,
                              hipStream_t stream)
{
    (void)in_sizes; (void)n_in; (void)out_size;
    const float* input = (const float*)d_in[0];   // [256,256,512]
    const float* w_ih  = (const float*)d_in[1];   // [1536,512]
    const float* w_hh  = (const float*)d_in[2];   // [1536,512]
    const float* b_ih  = (const float*)d_in[3];   // [1536]
    const float* b_hh  = (const float*)d_in[4];   // [1536]
    const float* W1    = (const float*)d_in[5];   // [512,512]
    const float* b1    = (const float*)d_in[6];   // [512]
    const float* W2    = (const float*)d_in[7];   // [512]
    const float* b2    = (const float*)d_in[8];   // [1]
    float* out = (float*)d_out;
    float* ws  = (float*)d_ws;

    // ws layout in FLOAT SLOTS. One [1536,512] bf16 buffer = 786432 ushorts
    // = 1,572,864 B = 393,216 float slots.
    float* hA = ws;                                        // [0, 131072)
    float* hB = ws + 131072;                               // [131072, 262144)
    float* o1 = ws + 262144;                               // [262144, 393216)
    unsigned short* wihH = (unsigned short*)(ws + 393216); // [393216, 786432)
    unsigned short* wihL = (unsigned short*)(ws + 786432); // [786432, 1179648)
    unsigned short* whhH = (unsigned short*)(ws + 1179648);// [1179648, 1572864)
    unsigned short* whhL = (unsigned short*)(ws + 1572864);// [1572864, 1966080)
    unsigned* flags = (unsigned*)(ws + 1966080);           // 16*32*32 u32 = 16384 slots
    float* gi = ws + 1982464;

    const size_t per_step = 256 * 1536;             // gi floats per timestep
    const size_t base = 1982464;
    const size_t avail = (ws_size / 4 > base) ? ws_size / 4 - base : 0;
    int Tc = (int)(avail / per_step);
    if (Tc > 256) Tc = 256;
    if (Tc < 1) Tc = 1;

    // Uniform state every launch/replay: h ping-pong AND flags zeroed.
    hipMemsetAsync(hA, 0, 262144 * sizeof(float), stream);      // hA + hB = 0
    hipMemsetAsync(flags, 0, 16384 * sizeof(unsigned), stream); // barrier gen 0

    cast_split<<<768, 256, 0, stream>>>(w_ih, wihH, wihL, 196608);
    cast_split<<<768, 256, 0, stream>>>(w_hh, whhH, whhL, 196608);

    for (int t0 = 0; t0 < 256; t0 += Tc) {
        const int tc = (t0 + Tc <= 256) ? Tc : (256 - t0);
        const int Mc = tc * 256;
        // Phase 1 (chunk): gi = X_chunk @ w_ih^T + b_ih
        gemm_gi_mfma<<<dim3(12, Mc / 128), 256, 0, stream>>>(
            input + (size_t)t0 * 256 * 512, wihH, wihL, b_ih, gi);
        // Phase 2 (chunk): coop persistent kernel + per-group barrier.
        {
            const float* a_gi = gi;
            const unsigned short* a_wh = whhH; const unsigned short* a_wl = whhL;
            const float* a_bh = b_hh;
            float* a_hA = hA; float* a_hB = hB;
            unsigned* a_fl = flags;
            int a_t0 = t0; int a_tc = tc;
            void* args[] = {&a_gi, &a_wh, &a_wl, &a_bh, &a_hA, &a_hB, &a_fl, &a_t0, &a_tc};
            hipError_t rc = hipLaunchCooperativeKernel(
                (const void*)gru_coop, dim3(512), dim3(256), args, 0, stream);
            if (rc != hipSuccess) {
                // Fallback: per-step launches (kernel boundary = grid barrier)
                for (int s = 0; s < tc; ++s) {
                    const int t = t0 + s;
                    const float* hold = (t & 1) ? hB : hA;
                    float* hnew = (t & 1) ? hA : hB;
                    gru_step_fb<<<dim3(512), 256, 0, stream>>>(
                        gi + (size_t)s * per_step, whhH, whhL, b_hh, hold, hnew);
                }
            }
        }
    }

    // Phase 3: final h is in hA (after 256 steps, even count).
    gemm_nt_bias<true><<<dim3(512 / 64, 256 / 64), 256, 0, stream>>>(
        hA, W1, b1, o1, 512, 512);
    value_head<<<256, 256, 0, stream>>>(o1, W2, b2, out);
}